// Round 8
// baseline (190.871 us; speedup 1.0000x reference)
//
#include <hip/hip_runtime.h>

// SlidingWindowAttention: B=1, S=4096, D=1024, H=16, d=64, WIN=512 (256 back / 255 fwd)
// Inputs/outputs FP32 storage (values bf16-rounded by harness).
//
// Pipeline:
//   0) cvt_all   : x|Wqkv|Wout -> bf16 into contiguous ws (one launch)
//   1) gemm_qkv  : 64x128 tile, BK=64, grid 1536 = 6 blocks/CU,
//                  scatters Q->Qb, K->Kp(pad), V->Vb
//   2) repack_v  : Vb -> VTp padded (h,d,key+256); zeroes Kp/VTp pads
//   3) swa_fused : 32 q/block, 2 waves, grid 2048 = 8 blocks/CU, 9 key
//                  tiles, gll16 staging, fixed-max softmax -> o
//   4) gemm_out  : 64x64 tile, BK=64, grid 1024 -> fp32 out
//
// LDS swizzle (all kernels): row of 64 bf16 = 8 chunks of 8; chunk c of row r
// lives in slot c ^ (r & 7). Row stride 128 B == 0 mod 32 banks -> bank
// depends only on slot -> gll16 DMA writes and b128 fragment reads are
// conflict-free.

typedef __bf16 bf16x8 __attribute__((ext_vector_type(8)));
typedef float f32x4 __attribute__((ext_vector_type(4)));
typedef unsigned short u16;
typedef unsigned int u32;

#define MFMA16(a, b, c) __builtin_amdgcn_mfma_f32_16x16x32_bf16(a, b, c, 0, 0, 0)

__device__ __forceinline__ u16 f2b(float f) {   // RNE f32 -> bf16 bits
  union { float f; u32 u; } x; x.f = f;
  u32 r = x.u + 0x7fffu + ((x.u >> 16) & 1u);
  return (u16)(r >> 16);
}

union U8x16 { int4 v; u16 u[8]; };

// async 16B global -> LDS (dest = wave-uniform base + lane*16, HW-generated)
__device__ __forceinline__ void gll16(const u16* g, u16* l) {
  __builtin_amdgcn_global_load_lds(
      (const __attribute__((address_space(1))) u16*)g,
      (__attribute__((address_space(3))) u16*)l, 16, 0, 0);
}

// ---------------------------------------------------------------------------
// fp32 -> bf16 for all three inputs in one launch. Destinations are
// contiguous in ws (xb | wqkvb | woutb), 1M chunks of 8 elements total.
// ---------------------------------------------------------------------------
__global__ void cvt_all(const float* __restrict__ x, const float* __restrict__ wqkv,
                        const float* __restrict__ wout, u16* __restrict__ dst)
{
  const int i = blockIdx.x * blockDim.x + threadIdx.x;   // chunk index
  const float* src; int off;
  if (i < 524288)       { src = x;    off = i; }           // 4096*1024/8
  else if (i < 917504)  { src = wqkv; off = i - 524288; }  // +3072*1024/8
  else                  { src = wout; off = i - 917504; }  // +1024*1024/8
  const float4 a = ((const float4*)src)[off * 2];
  const float4 b = ((const float4*)src)[off * 2 + 1];
  U8x16 t;
  t.u[0] = f2b(a.x); t.u[1] = f2b(a.y); t.u[2] = f2b(a.z); t.u[3] = f2b(a.w);
  t.u[4] = f2b(b.x); t.u[5] = f2b(b.y); t.u[6] = f2b(b.z); t.u[7] = f2b(b.w);
  ((int4*)dst)[i] = t.v;
}

// ---------------------------------------------------------------------------
// QKV GEMM: 64x128 tile, BK=64, grid (24, 64) = 1536 blocks = 6/CU
// (__launch_bounds__(256,6), LDS 24 KB, VGPR ~40). 2x2 waves, each 32x64:
// 2x4 MFMA tiles x 2 K-halves = 16 MFMA per barrier-round, 16 rounds.
// Epilogue scatters: Q (n<1024) -> Qb; K -> Kp (h, key+256, d); V -> Vb.
// ---------------------------------------------------------------------------
__global__ __launch_bounds__(256, 6) void gemm_qkv(
    const u16* __restrict__ A, const u16* __restrict__ B,
    const float* __restrict__ bias,
    u16* __restrict__ Qb, u16* __restrict__ Kp, u16* __restrict__ Vb)
{
  __shared__ u16 As[64 * 64];    // 8 KB
  __shared__ u16 Bs[128 * 64];   // 16 KB

  const int K = 1024;
  const int tid  = threadIdx.x;
  const int lane = tid & 63;
  const int wave = tid >> 6;
  const int quad = lane >> 4;
  const int c16  = lane & 15;
  const int wr   = wave >> 1;            // M half (32 rows)
  const int wc   = wave & 1;             // N half (64 cols)
  const long m0 = (long)blockIdx.y * 64;
  const long n0 = (long)blockIdx.x * 128;

  // staging lane map: lane i -> row grp+(i>>3), slot i&7, global chunk
  // (i&7)^((i>>3)&7). One gll16 = 8 rows x 8 slots = 1 KB.
  const int rowo   = lane >> 3;
  const int schunk = (lane & 7) ^ rowo;
  const u16* gA0 = &A[(m0 + wave * 16 + rowo) * K + schunk * 8];
  const u16* gA1 = gA0 + 8 * K;
  const u16* gB0 = &B[(n0 + wave * 32 + rowo) * K + schunk * 8];
  const u16* gB1 = gB0 + 8 * K;
  const u16* gB2 = gB0 + 16 * K;
  const u16* gB3 = gB0 + 24 * K;
  u16* const lA0 = &As[(wave * 16) * 64];
  u16* const lA1 = lA0 + 8 * 64;
  u16* const lB0 = &Bs[(wave * 32) * 64];
  u16* const lB1 = lB0 + 8 * 64;
  u16* const lB2 = lB0 + 16 * 64;
  u16* const lB3 = lB0 + 24 * 64;

  const int rsw  = c16 & 7;
  const int off0 = (quad ^ rsw) * 8;
  const int off1 = ((4 + quad) ^ rsw) * 8;
  const u16* rA[2]; const u16* rB[4];
#pragma unroll
  for (int i = 0; i < 2; ++i) rA[i] = &As[(wr * 32 + i * 16 + c16) * 64];
#pragma unroll
  for (int j = 0; j < 4; ++j) rB[j] = &Bs[(wc * 64 + j * 16 + c16) * 64];

  f32x4 acc[2][4];
#pragma unroll
  for (int i = 0; i < 2; ++i)
#pragma unroll
    for (int j = 0; j < 4; ++j)
      acc[i][j] = f32x4{0.f, 0.f, 0.f, 0.f};

  for (int k0 = 0; k0 < K; k0 += 64) {
    __syncthreads();
    gll16(gA0, lA0); gll16(gA1, lA1);
    gll16(gB0, lB0); gll16(gB1, lB1); gll16(gB2, lB2); gll16(gB3, lB3);
    gA0 += 64; gA1 += 64; gB0 += 64; gB1 += 64; gB2 += 64; gB3 += 64;
    __syncthreads();

#pragma unroll
    for (int h = 0; h < 2; ++h) {
      const int off = h ? off1 : off0;
      bf16x8 af[2], bfr[4];
#pragma unroll
      for (int i = 0; i < 2; ++i) af[i]  = *(const bf16x8*)(rA[i] + off);
#pragma unroll
      for (int j = 0; j < 4; ++j) bfr[j] = *(const bf16x8*)(rB[j] + off);
#pragma unroll
      for (int i = 0; i < 2; ++i)
#pragma unroll
        for (int j = 0; j < 4; ++j)
          acc[i][j] = MFMA16(af[i], bfr[j], acc[i][j]);
    }
  }

  const int region = (int)(n0 >> 10);      // 0=Q, 1=K, 2=V (block-uniform)
#pragma unroll
  for (int i = 0; i < 2; ++i) {
    const long row0 = m0 + wr * 32 + i * 16 + quad * 4;
#pragma unroll
    for (int j = 0; j < 4; ++j) {
      const long col = n0 + wc * 64 + j * 16 + c16;
      const float bv = bias[col];
#pragma unroll
      for (int r = 0; r < 4; ++r) {
        const u16 v = f2b(acc[i][j][r] + bv);
        const long row = row0 + r;
        if (region == 0) {
          Qb[row * 1024 + col] = v;
        } else if (region == 1) {
          const int n1 = (int)(col - 1024);
          const int h = n1 >> 6, d = n1 & 63;
          Kp[((long)h * 4608 + row + 256) * 64 + d] = v;
        } else {
          Vb[row * 1024 + (col - 2048)] = v;
        }
      }
    }
  }
}

// ---------------------------------------------------------------------------
// Output GEMM: 64x64 tile, BK=64, grid (16, 64) = 1024 blocks = 4/CU.
// 2x2 waves, each 32x32: 2x2 MFMA tiles x 2 K-halves = 8 MFMA/round. fp32 out.
// ---------------------------------------------------------------------------
__global__ __launch_bounds__(256, 4) void gemm_out(
    const u16* __restrict__ A, const u16* __restrict__ B,
    const float* __restrict__ bias, float* __restrict__ C)
{
  __shared__ u16 As[64 * 64];    // 8 KB
  __shared__ u16 Bs[64 * 64];    // 8 KB

  const int K = 1024, N = 1024;
  const int tid  = threadIdx.x;
  const int lane = tid & 63;
  const int wave = tid >> 6;
  const int quad = lane >> 4;
  const int c16  = lane & 15;
  const int wr   = wave >> 1;
  const int wc   = wave & 1;
  const long m0 = (long)blockIdx.y * 64;
  const long n0 = (long)blockIdx.x * 64;

  const int rowo   = lane >> 3;
  const int schunk = (lane & 7) ^ rowo;
  const u16* gA0 = &A[(m0 + wave * 16 + rowo) * K + schunk * 8];
  const u16* gA1 = gA0 + 8 * K;
  const u16* gB0 = &B[(n0 + wave * 16 + rowo) * K + schunk * 8];
  const u16* gB1 = gB0 + 8 * K;
  u16* const lA0 = &As[(wave * 16) * 64];
  u16* const lA1 = lA0 + 8 * 64;
  u16* const lB0 = &Bs[(wave * 16) * 64];
  u16* const lB1 = lB0 + 8 * 64;

  const int rsw  = c16 & 7;
  const int off0 = (quad ^ rsw) * 8;
  const int off1 = ((4 + quad) ^ rsw) * 8;
  const u16* rA[2]; const u16* rB[2];
#pragma unroll
  for (int i = 0; i < 2; ++i) {
    rA[i] = &As[(wr * 32 + i * 16 + c16) * 64];
    rB[i] = &Bs[(wc * 32 + i * 16 + c16) * 64];
  }

  f32x4 acc[2][2];
#pragma unroll
  for (int i = 0; i < 2; ++i)
#pragma unroll
    for (int j = 0; j < 2; ++j)
      acc[i][j] = f32x4{0.f, 0.f, 0.f, 0.f};

  for (int k0 = 0; k0 < K; k0 += 64) {
    __syncthreads();
    gll16(gA0, lA0); gll16(gA1, lA1);
    gll16(gB0, lB0); gll16(gB1, lB1);
    gA0 += 64; gA1 += 64; gB0 += 64; gB1 += 64;
    __syncthreads();

#pragma unroll
    for (int h = 0; h < 2; ++h) {
      const int off = h ? off1 : off0;
      bf16x8 af[2], bfr[2];
#pragma unroll
      for (int i = 0; i < 2; ++i) af[i]  = *(const bf16x8*)(rA[i] + off);
#pragma unroll
      for (int j = 0; j < 2; ++j) bfr[j] = *(const bf16x8*)(rB[j] + off);
#pragma unroll
      for (int i = 0; i < 2; ++i)
#pragma unroll
        for (int j = 0; j < 2; ++j)
          acc[i][j] = MFMA16(af[i], bfr[j], acc[i][j]);
    }
  }

#pragma unroll
  for (int i = 0; i < 2; ++i) {
    const long row0 = m0 + wr * 32 + i * 16 + quad * 4;
#pragma unroll
    for (int j = 0; j < 2; ++j) {
      const long col = n0 + wc * 32 + j * 16 + c16;
      const float bv = bias[col];
#pragma unroll
      for (int r = 0; r < 4; ++r)
        C[(row0 + r) * N + col] = acc[i][j][r] + bv;
    }
  }
}

// ---------------------------------------------------------------------------
// V repack: Vb(S,D) -> VTp(h, d, key+256) transposed; zeroes pad tiles of
// both Kp and VTp. Grid (72 padded key tiles, 16 heads), 256 threads.
// Dual-XOR swizzled LDS transpose -> both write and read conflict-free.
// ---------------------------------------------------------------------------
__global__ __launch_bounds__(256, 2) void repack_v(
    const u16* __restrict__ Vb, u16* __restrict__ Kp, u16* __restrict__ VTp)
{
  __shared__ u16 lds[64 * 64];
  const int tile = blockIdx.x;          // padded key tile, 0..71
  const int h    = blockIdx.y;
  const int tid  = threadIdx.x;
  const int kt   = tile * 64 - 256;     // actual key start
  const long vtb = (long)h * 64 * 4608;

  if (kt < 0 || kt >= 4096) {           // pad tile: zero Kp rows + VTp cols
    const int4 z = {0, 0, 0, 0};
    for (int idx = tid; idx < 512; idx += 256) {
      const int r = idx >> 3, c = idx & 7;
      *(int4*)(&Kp[((long)h * 4608 + tile * 64 + r) * 64 + c * 8]) = z;
      *(int4*)(&VTp[vtb + (long)r * 4608 + tile * 64 + c * 8])     = z;
    }
    return;
  }

  for (int idx = tid; idx < 512; idx += 256) {
    const int r = idx >> 3, c = idx & 7;            // key r, d-chunk c
    U8x16 t; t.v = *(const int4*)(&Vb[(long)(kt + r) * 1024 + h * 64 + c * 8]);
#pragma unroll
    for (int j = 0; j < 8; ++j) {
      const int d = c * 8 + j;
      lds[d * 64 + (((r >> 3) ^ ((c + j) & 7)) * 8) + (r & 7)] = t.u[j];
    }
  }
  __syncthreads();
  for (int idx = tid; idx < 512; idx += 256) {
    const int d = idx >> 3, c2 = idx & 7;           // d row, key-chunk c2
    const int sl = (c2 ^ ((d + (d >> 3)) & 7)) * 8;
    const int4 v = *(const int4*)(&lds[d * 64 + sl]);
    *(int4*)(&VTp[vtb + (long)d * 4608 + 256 + kt + c2 * 8]) = v;
  }
}

// ---------------------------------------------------------------------------
// Sliding-window flash attention. Grid (S/32, H) = 2048 blocks, 128 thr =
// 2 waves -> 8 blocks/CU (LDS 20 KB x 8 = 160 KB exactly). Wave w owns
// queries [qb0+16w, +16). 9 key tiles of 64 cover padded keys [qb0, qb0+576);
// both waves use all 9 tiles (no skip: max needed = qb0+542 < 576).
// Fixed-max softmax (|s| <~ 8 << 88): p = exp(s/8); pad keys (k=0,v=0) give
// p=1 in denominator, matching reference zero-padding exactly.
// P per-wave in LDS (C-layout -> A-layout), slot-swizzled.
// ---------------------------------------------------------------------------
__global__ __launch_bounds__(128, 4) void swa_fused(
    const u16* __restrict__ Qb, const u16* __restrict__ Kp,
    const u16* __restrict__ VTp, u16* __restrict__ o)
{
  __shared__ u16 Ks[64 * 64];       // (key, d), slot-swizzled   8 KB
  __shared__ u16 Vs[64 * 64];       // (d, key), slot-swizzled   8 KB
  __shared__ u16 Ps[2 * 16 * 64];   // per-wave (q, key)          4 KB

  const int tid  = threadIdx.x;
  const int lane = tid & 63;
  const int w    = tid >> 6;        // 0,1
  const int quad = lane >> 4;
  const int c16  = lane & 15;
  const int h    = blockIdx.y;
  const int qb0  = blockIdx.x * 32;

  // Q fragments (A-layout), loaded once
  const long qrow = qb0 + w * 16 + c16;
  const bf16x8 aq0 = *(const bf16x8*)(&Qb[qrow * 1024 + h * 64 + quad * 8]);
  const bf16x8 aq1 = *(const bf16x8*)(&Qb[qrow * 1024 + h * 64 + 32 + quad * 8]);

  // staging: wave w covers rows [w*32, +32) of Ks and Vs -> 4 gll16 each
  const int rowo   = lane >> 3;
  const int gchunk = (lane & 7) ^ rowo;
  const u16* gK[4]; const u16* gV[4];
  u16* lK[4]; u16* lV[4];
#pragma unroll
  for (int i = 0; i < 4; ++i) {
    gK[i] = &Kp[((long)h * 4608 + qb0 + w * 32 + i * 8 + rowo) * 64 + gchunk * 8];
    gV[i] = &VTp[((long)h * 64 + w * 32 + i * 8 + rowo) * 4608 + qb0 + gchunk * 8];
    lK[i] = &Ks[(w * 32 + i * 8) * 64];
    lV[i] = &Vs[(w * 32 + i * 8) * 64];
  }

  const int rsw  = c16 & 7;
  const int off0 = (quad ^ rsw) * 8;
  const int off1 = ((4 + quad) ^ rsw) * 8;
  const u16* rK[4]; const u16* rV[4];
#pragma unroll
  for (int i = 0; i < 4; ++i) {
    rK[i] = &Ks[(i * 16 + c16) * 64];
    rV[i] = &Vs[(i * 16 + c16) * 64];
  }
  u16* const Pw = &Ps[w * 1024];
  const u16* rP = &Pw[c16 * 64];

  const int dbase = c16 - 16 * w - quad * 4;   // delta = dbase + t*64 + tcol*16 - r

  f32x4 acc[4];
#pragma unroll
  for (int dt = 0; dt < 4; ++dt) acc[dt] = f32x4{0.f, 0.f, 0.f, 0.f};
  float rsum[4] = {0.f, 0.f, 0.f, 0.f};

  for (int t = 0; t < 9; ++t) {
    __syncthreads();
#pragma unroll
    for (int i = 0; i < 4; ++i) { gll16(gK[i], lK[i]); gK[i] += 64 * 64; }
#pragma unroll
    for (int i = 0; i < 4; ++i) { gll16(gV[i], lV[i]); gV[i] += 64; }
    __syncthreads();

    // S = Q K^T ; mask+exp ; P -> LDS (per-wave, same-wave RAW via lgkmcnt)
#pragma unroll
    for (int tcol = 0; tcol < 4; ++tcol) {
      const bf16x8 bk0 = *(const bf16x8*)(rK[tcol] + off0);
      const bf16x8 bk1 = *(const bf16x8*)(rK[tcol] + off1);
      f32x4 s = f32x4{0.f, 0.f, 0.f, 0.f};
      s = MFMA16(aq0, bk0, s);
      s = MFMA16(aq1, bk1, s);
#pragma unroll
      for (int r = 0; r < 4; ++r) {
        const int delta = dbase + t * 64 + tcol * 16 - r;
        const float p = ((u32)delta < 512u) ? __expf(s[r] * 0.125f) : 0.f;
        rsum[r] += p;
        const int qi = quad * 4 + r;
        const int kc = tcol * 16 + c16;
        Pw[qi * 64 + (((kc >> 3) ^ (qi & 7)) * 8) + (kc & 7)] = f2b(p);
      }
    }

    // O += P V
    const bf16x8 ap0 = *(const bf16x8*)(rP + off0);
    const bf16x8 ap1 = *(const bf16x8*)(rP + off1);
#pragma unroll
    for (int dt = 0; dt < 4; ++dt) {
      const bf16x8 bv0 = *(const bf16x8*)(rV[dt] + off0);
      const bf16x8 bv1 = *(const bf16x8*)(rV[dt] + off1);
      acc[dt] = MFMA16(ap0, bv0, acc[dt]);
      acc[dt] = MFMA16(ap1, bv1, acc[dt]);
    }
  }

  // row-sum reduction across the 16 lanes holding each C-row
#pragma unroll
  for (int off = 1; off < 16; off <<= 1)
#pragma unroll
    for (int r = 0; r < 4; ++r)
      rsum[r] += __shfl_xor(rsum[r], off, 64);

  const int qp = qb0 + w * 16 + quad * 4;
#pragma unroll
  for (int r = 0; r < 4; ++r) {
    const float inv = 1.f / rsum[r];
#pragma unroll
    for (int dt = 0; dt < 4; ++dt)
      o[(long)(qp + r) * 1024 + h * 64 + dt * 16 + c16] = f2b(acc[dt][r] * inv);
  }
}

// ---------------------------------------------------------------------------
extern "C" void kernel_launch(void* const* d_in, const int* in_sizes, int n_in,
                              void* d_out, int out_size, void* d_ws, size_t ws_size,
                              hipStream_t stream)
{
  const float* x    = (const float*)d_in[0];   // (4096, 1024)
  const float* Wqkv = (const float*)d_in[1];   // (3072, 1024)
  const float* bqkv = (const float*)d_in[2];   // (3072,)
  const float* Wout = (const float*)d_in[3];   // (1024, 1024)
  const float* bout = (const float*)d_in[4];   // (1024,)
  float* out = (float*)d_out;                  // (4096, 1024)

  // ws layout (u16 elements): 52.4 MB total; xb|wqkvb|woutb contiguous
  u16* xb    = (u16*)d_ws;                         // 4096*1024
  u16* wqkvb = xb    + (size_t)4096 * 1024;        // 3072*1024
  u16* woutb = wqkvb + (size_t)3072 * 1024;        // 1024*1024
  u16* Qb    = woutb + (size_t)1024 * 1024;        // 4096*1024
  u16* Kp    = Qb    + (size_t)4096 * 1024;        // 16*4608*64
  u16* VTp   = Kp    + (size_t)16 * 4608 * 64;     // 16*64*4608
  u16* Vb    = VTp   + (size_t)16 * 4608 * 64;     // 4096*1024 (o aliases)
  u16* o     = Vb;                                 // Vb dead after repack_v

  cvt_all<<<1048576 / 256, 256, 0, stream>>>(x, Wqkv, Wout, xb);

  gemm_qkv<<<dim3(3072 / 128, 4096 / 64), 256, 0, stream>>>(
      xb, wqkvb, bqkv, Qb, Kp, Vb);
  repack_v<<<dim3(72, 16), 256, 0, stream>>>(Vb, Kp, VTp);
  swa_fused<<<dim3(4096 / 32, 16), 128, 0, stream>>>(Qb, Kp, VTp, o);
  gemm_out<<<dim3(1024 / 64, 4096 / 64), 256, 0, stream>>>(o, woutb, bout, out);
}

// Round 9
// 164.997 us; speedup vs baseline: 1.1568x; 1.1568x over previous
//
#include <hip/hip_runtime.h>

// SlidingWindowAttention: B=1, S=4096, D=1024, H=16, d=64, WIN=512 (256 back / 255 fwd)
// Inputs/outputs FP32 storage (values bf16-rounded by harness).
//
// Pipeline:
//   0) cvt_all   : x|Wqkv|Wout -> bf16 into contiguous ws (one launch)
//   1) gemm_qkv  : 64x128 tile, BK=64, grid 1536 = 6 blocks/CU,
//                  scatters Q->Qb, K->Kp(pad), V->Vb
//   2) repack_v  : Vb -> VTp padded (h,d,key+256); zeroes Kp/VTp pads
//   3) swa_fused : 64 q/block, 4 waves, flat grid 1024 with XCD-locality
//                  swizzle (XCD x <- heads {2x,2x+1}, qb ascending) so K/V
//                  stream through the per-XCD L2 once per head
//   4) gemm_out  : 64x64 tile, BK=64, grid 1024 -> fp32 out
//
// LDS swizzle (all kernels): row of 64 bf16 = 8 chunks of 8; chunk c of row r
// lives in slot c ^ (r & 7). Row stride 128 B == 0 mod 32 banks -> bank
// depends only on slot -> gll16 DMA writes and b128 fragment reads are
// conflict-free.

typedef __bf16 bf16x8 __attribute__((ext_vector_type(8)));
typedef float f32x4 __attribute__((ext_vector_type(4)));
typedef unsigned short u16;
typedef unsigned int u32;

#define MFMA16(a, b, c) __builtin_amdgcn_mfma_f32_16x16x32_bf16(a, b, c, 0, 0, 0)

__device__ __forceinline__ u16 f2b(float f) {   // RNE f32 -> bf16 bits
  union { float f; u32 u; } x; x.f = f;
  u32 r = x.u + 0x7fffu + ((x.u >> 16) & 1u);
  return (u16)(r >> 16);
}

union U8x16 { int4 v; u16 u[8]; };

// async 16B global -> LDS (dest = wave-uniform base + lane*16, HW-generated)
__device__ __forceinline__ void gll16(const u16* g, u16* l) {
  __builtin_amdgcn_global_load_lds(
      (const __attribute__((address_space(1))) u16*)g,
      (__attribute__((address_space(3))) u16*)l, 16, 0, 0);
}

// ---------------------------------------------------------------------------
// fp32 -> bf16 for all three inputs in one launch. Destinations are
// contiguous in ws (xb | wqkvb | woutb), 1M chunks of 8 elements total.
// ---------------------------------------------------------------------------
__global__ void cvt_all(const float* __restrict__ x, const float* __restrict__ wqkv,
                        const float* __restrict__ wout, u16* __restrict__ dst)
{
  const int i = blockIdx.x * blockDim.x + threadIdx.x;   // chunk index
  const float* src; int off;
  if (i < 524288)       { src = x;    off = i; }           // 4096*1024/8
  else if (i < 917504)  { src = wqkv; off = i - 524288; }  // +3072*1024/8
  else                  { src = wout; off = i - 917504; }  // +1024*1024/8
  const float4 a = ((const float4*)src)[off * 2];
  const float4 b = ((const float4*)src)[off * 2 + 1];
  U8x16 t;
  t.u[0] = f2b(a.x); t.u[1] = f2b(a.y); t.u[2] = f2b(a.z); t.u[3] = f2b(a.w);
  t.u[4] = f2b(b.x); t.u[5] = f2b(b.y); t.u[6] = f2b(b.z); t.u[7] = f2b(b.w);
  ((int4*)dst)[i] = t.v;
}

// ---------------------------------------------------------------------------
// QKV GEMM: 64x128 tile, BK=64, grid (24, 64) = 1536 blocks = 6/CU
// (__launch_bounds__(256,6), LDS 24 KB). 2x2 waves, each 32x64:
// 2x4 MFMA tiles x 2 K-halves = 16 MFMA per barrier-round, 16 rounds.
// Epilogue scatters: Q (n<1024) -> Qb; K -> Kp (h, key+256, d); V -> Vb.
// ---------------------------------------------------------------------------
__global__ __launch_bounds__(256, 6) void gemm_qkv(
    const u16* __restrict__ A, const u16* __restrict__ B,
    const float* __restrict__ bias,
    u16* __restrict__ Qb, u16* __restrict__ Kp, u16* __restrict__ Vb)
{
  __shared__ u16 As[64 * 64];    // 8 KB
  __shared__ u16 Bs[128 * 64];   // 16 KB

  const int K = 1024;
  const int tid  = threadIdx.x;
  const int lane = tid & 63;
  const int wave = tid >> 6;
  const int quad = lane >> 4;
  const int c16  = lane & 15;
  const int wr   = wave >> 1;            // M half (32 rows)
  const int wc   = wave & 1;             // N half (64 cols)
  const long m0 = (long)blockIdx.y * 64;
  const long n0 = (long)blockIdx.x * 128;

  const int rowo   = lane >> 3;
  const int schunk = (lane & 7) ^ rowo;
  const u16* gA0 = &A[(m0 + wave * 16 + rowo) * K + schunk * 8];
  const u16* gA1 = gA0 + 8 * K;
  const u16* gB0 = &B[(n0 + wave * 32 + rowo) * K + schunk * 8];
  const u16* gB1 = gB0 + 8 * K;
  const u16* gB2 = gB0 + 16 * K;
  const u16* gB3 = gB0 + 24 * K;
  u16* const lA0 = &As[(wave * 16) * 64];
  u16* const lA1 = lA0 + 8 * 64;
  u16* const lB0 = &Bs[(wave * 32) * 64];
  u16* const lB1 = lB0 + 8 * 64;
  u16* const lB2 = lB0 + 16 * 64;
  u16* const lB3 = lB0 + 24 * 64;

  const int rsw  = c16 & 7;
  const int off0 = (quad ^ rsw) * 8;
  const int off1 = ((4 + quad) ^ rsw) * 8;
  const u16* rA[2]; const u16* rB[4];
#pragma unroll
  for (int i = 0; i < 2; ++i) rA[i] = &As[(wr * 32 + i * 16 + c16) * 64];
#pragma unroll
  for (int j = 0; j < 4; ++j) rB[j] = &Bs[(wc * 64 + j * 16 + c16) * 64];

  f32x4 acc[2][4];
#pragma unroll
  for (int i = 0; i < 2; ++i)
#pragma unroll
    for (int j = 0; j < 4; ++j)
      acc[i][j] = f32x4{0.f, 0.f, 0.f, 0.f};

  for (int k0 = 0; k0 < K; k0 += 64) {
    __syncthreads();
    gll16(gA0, lA0); gll16(gA1, lA1);
    gll16(gB0, lB0); gll16(gB1, lB1); gll16(gB2, lB2); gll16(gB3, lB3);
    gA0 += 64; gA1 += 64; gB0 += 64; gB1 += 64; gB2 += 64; gB3 += 64;
    __syncthreads();

#pragma unroll
    for (int h = 0; h < 2; ++h) {
      const int off = h ? off1 : off0;
      bf16x8 af[2], bfr[4];
#pragma unroll
      for (int i = 0; i < 2; ++i) af[i]  = *(const bf16x8*)(rA[i] + off);
#pragma unroll
      for (int j = 0; j < 4; ++j) bfr[j] = *(const bf16x8*)(rB[j] + off);
#pragma unroll
      for (int i = 0; i < 2; ++i)
#pragma unroll
        for (int j = 0; j < 4; ++j)
          acc[i][j] = MFMA16(af[i], bfr[j], acc[i][j]);
    }
  }

  const int region = (int)(n0 >> 10);      // 0=Q, 1=K, 2=V (block-uniform)
#pragma unroll
  for (int i = 0; i < 2; ++i) {
    const long row0 = m0 + wr * 32 + i * 16 + quad * 4;
#pragma unroll
    for (int j = 0; j < 4; ++j) {
      const long col = n0 + wc * 64 + j * 16 + c16;
      const float bv = bias[col];
#pragma unroll
      for (int r = 0; r < 4; ++r) {
        const u16 v = f2b(acc[i][j][r] + bv);
        const long row = row0 + r;
        if (region == 0) {
          Qb[row * 1024 + col] = v;
        } else if (region == 1) {
          const int n1 = (int)(col - 1024);
          const int h = n1 >> 6, d = n1 & 63;
          Kp[((long)h * 4608 + row + 256) * 64 + d] = v;
        } else {
          Vb[row * 1024 + (col - 2048)] = v;
        }
      }
    }
  }
}

// ---------------------------------------------------------------------------
// Output GEMM: 64x64 tile, BK=64, grid (16, 64) = 1024 blocks = 4/CU.
// 2x2 waves, each 32x32: 2x2 MFMA tiles x 2 K-halves = 8 MFMA/round. fp32 out.
// ---------------------------------------------------------------------------
__global__ __launch_bounds__(256, 4) void gemm_out(
    const u16* __restrict__ A, const u16* __restrict__ B,
    const float* __restrict__ bias, float* __restrict__ C)
{
  __shared__ u16 As[64 * 64];    // 8 KB
  __shared__ u16 Bs[64 * 64];    // 8 KB

  const int K = 1024, N = 1024;
  const int tid  = threadIdx.x;
  const int lane = tid & 63;
  const int wave = tid >> 6;
  const int quad = lane >> 4;
  const int c16  = lane & 15;
  const int wr   = wave >> 1;
  const int wc   = wave & 1;
  const long m0 = (long)blockIdx.y * 64;
  const long n0 = (long)blockIdx.x * 64;

  const int rowo   = lane >> 3;
  const int schunk = (lane & 7) ^ rowo;
  const u16* gA0 = &A[(m0 + wave * 16 + rowo) * K + schunk * 8];
  const u16* gA1 = gA0 + 8 * K;
  const u16* gB0 = &B[(n0 + wave * 16 + rowo) * K + schunk * 8];
  const u16* gB1 = gB0 + 8 * K;
  u16* const lA0 = &As[(wave * 16) * 64];
  u16* const lA1 = lA0 + 8 * 64;
  u16* const lB0 = &Bs[(wave * 16) * 64];
  u16* const lB1 = lB0 + 8 * 64;

  const int rsw  = c16 & 7;
  const int off0 = (quad ^ rsw) * 8;
  const int off1 = ((4 + quad) ^ rsw) * 8;
  const u16* rA[2]; const u16* rB[2];
#pragma unroll
  for (int i = 0; i < 2; ++i) {
    rA[i] = &As[(wr * 32 + i * 16 + c16) * 64];
    rB[i] = &Bs[(wc * 32 + i * 16 + c16) * 64];
  }

  f32x4 acc[2][2];
#pragma unroll
  for (int i = 0; i < 2; ++i)
#pragma unroll
    for (int j = 0; j < 2; ++j)
      acc[i][j] = f32x4{0.f, 0.f, 0.f, 0.f};

  for (int k0 = 0; k0 < K; k0 += 64) {
    __syncthreads();
    gll16(gA0, lA0); gll16(gA1, lA1);
    gll16(gB0, lB0); gll16(gB1, lB1);
    gA0 += 64; gA1 += 64; gB0 += 64; gB1 += 64;
    __syncthreads();

#pragma unroll
    for (int h = 0; h < 2; ++h) {
      const int off = h ? off1 : off0;
      bf16x8 af[2], bfr[2];
#pragma unroll
      for (int i = 0; i < 2; ++i) af[i]  = *(const bf16x8*)(rA[i] + off);
#pragma unroll
      for (int j = 0; j < 2; ++j) bfr[j] = *(const bf16x8*)(rB[j] + off);
#pragma unroll
      for (int i = 0; i < 2; ++i)
#pragma unroll
        for (int j = 0; j < 2; ++j)
          acc[i][j] = MFMA16(af[i], bfr[j], acc[i][j]);
    }
  }

#pragma unroll
  for (int i = 0; i < 2; ++i) {
    const long row0 = m0 + wr * 32 + i * 16 + quad * 4;
#pragma unroll
    for (int j = 0; j < 2; ++j) {
      const long col = n0 + wc * 32 + j * 16 + c16;
      const float bv = bias[col];
#pragma unroll
      for (int r = 0; r < 4; ++r)
        C[(row0 + r) * N + col] = acc[i][j][r] + bv;
    }
  }
}

// ---------------------------------------------------------------------------
// V repack: Vb(S,D) -> VTp(h, d, key+256) transposed; zeroes pad tiles of
// both Kp and VTp. Grid (72 padded key tiles, 16 heads), 256 threads.
// Dual-XOR swizzled LDS transpose -> both write and read conflict-free.
// ---------------------------------------------------------------------------
__global__ __launch_bounds__(256, 2) void repack_v(
    const u16* __restrict__ Vb, u16* __restrict__ Kp, u16* __restrict__ VTp)
{
  __shared__ u16 lds[64 * 64];
  const int tile = blockIdx.x;          // padded key tile, 0..71
  const int h    = blockIdx.y;
  const int tid  = threadIdx.x;
  const int kt   = tile * 64 - 256;     // actual key start
  const long vtb = (long)h * 64 * 4608;

  if (kt < 0 || kt >= 4096) {           // pad tile: zero Kp rows + VTp cols
    const int4 z = {0, 0, 0, 0};
    for (int idx = tid; idx < 512; idx += 256) {
      const int r = idx >> 3, c = idx & 7;
      *(int4*)(&Kp[((long)h * 4608 + tile * 64 + r) * 64 + c * 8]) = z;
      *(int4*)(&VTp[vtb + (long)r * 4608 + tile * 64 + c * 8])     = z;
    }
    return;
  }

  for (int idx = tid; idx < 512; idx += 256) {
    const int r = idx >> 3, c = idx & 7;            // key r, d-chunk c
    U8x16 t; t.v = *(const int4*)(&Vb[(long)(kt + r) * 1024 + h * 64 + c * 8]);
#pragma unroll
    for (int j = 0; j < 8; ++j) {
      const int d = c * 8 + j;
      lds[d * 64 + (((r >> 3) ^ ((c + j) & 7)) * 8) + (r & 7)] = t.u[j];
    }
  }
  __syncthreads();
  for (int idx = tid; idx < 512; idx += 256) {
    const int d = idx >> 3, c2 = idx & 7;           // d row, key-chunk c2
    const int sl = (c2 ^ ((d + (d >> 3)) & 7)) * 8;
    const int4 v = *(const int4*)(&lds[d * 64 + sl]);
    *(int4*)(&VTp[vtb + (long)d * 4608 + 256 + kt + c2 * 8]) = v;
  }
}

// ---------------------------------------------------------------------------
// Sliding-window flash attention. Flat grid 1024 blocks, 256 thr = 4 waves
// (4 blocks/CU, LDS 24 KB). XCD-locality swizzle: HW dispatches workgroups
// round-robin over 8 XCDs by linear block ID, so xcd = b & 7 is (heuristically)
// the XCD. We give XCD x heads {2x, 2x+1} with qb ascending: the ~32
// concurrently-resident blocks per XCD then share a sliding ~1k-key window
// (~0.8 MB K+V) inside the 4 MB per-XCD L2 -> K/V fetched from HBM ~once.
// Wave w owns queries [qb0+16w, +16). 9 key tiles of 64 cover padded keys
// [qb0, qb0+576); all waves use all 9 tiles.
// Fixed-max softmax (|s| <~ 8 << 88): p = exp(s/8); pad keys (k=0,v=0) give
// p=1 in denominator, matching reference zero-padding exactly.
// P per-wave in LDS (C-layout -> A-layout), slot-swizzled.
// ---------------------------------------------------------------------------
__global__ __launch_bounds__(256, 4) void swa_fused(
    const u16* __restrict__ Qb, const u16* __restrict__ Kp,
    const u16* __restrict__ VTp, u16* __restrict__ o)
{
  __shared__ u16 Ks[64 * 64];       // (key, d), slot-swizzled   8 KB
  __shared__ u16 Vs[64 * 64];       // (d, key), slot-swizzled   8 KB
  __shared__ u16 Ps[4 * 16 * 64];   // per-wave (q, key)          8 KB

  const int tid  = threadIdx.x;
  const int lane = tid & 63;
  const int w    = tid >> 6;
  const int quad = lane >> 4;
  const int c16  = lane & 15;

  // XCD-locality remap: b -> (h, qb0)
  const int b    = blockIdx.x;
  const int xcd  = b & 7;
  const int idx  = b >> 3;               // 0..127, ascending in launch order
  const int h    = xcd * 2 + (idx >> 6); // heads {2x, 2x+1}
  const int qb0  = (idx & 63) * 64;      // qb ascending within XCD

  const long qrow = qb0 + w * 16 + c16;
  const bf16x8 aq0 = *(const bf16x8*)(&Qb[qrow * 1024 + h * 64 + quad * 8]);
  const bf16x8 aq1 = *(const bf16x8*)(&Qb[qrow * 1024 + h * 64 + 32 + quad * 8]);

  // staging: wave w covers rows [w*16, +16) of Ks (keys) and Vs (d), 2 gll16 each
  const int rowo   = lane >> 3;
  const int gchunk = (lane & 7) ^ rowo;
  const u16* gK0 = &Kp[((long)h * 4608 + qb0 + w * 16 + rowo) * 64 + gchunk * 8];
  const u16* gK1 = gK0 + 8 * 64;
  const u16* gV0 = &VTp[((long)h * 64 + w * 16 + rowo) * 4608 + qb0 + gchunk * 8];
  const u16* gV1 = gV0 + 8 * 4608;
  u16* const lK0 = &Ks[(w * 16) * 64];
  u16* const lK1 = lK0 + 8 * 64;
  u16* const lV0 = &Vs[(w * 16) * 64];
  u16* const lV1 = lV0 + 8 * 64;

  const int rsw  = c16 & 7;
  const int off0 = (quad ^ rsw) * 8;
  const int off1 = ((4 + quad) ^ rsw) * 8;
  const u16* rK[4]; const u16* rV[4];
#pragma unroll
  for (int i = 0; i < 4; ++i) {
    rK[i] = &Ks[(i * 16 + c16) * 64];
    rV[i] = &Vs[(i * 16 + c16) * 64];
  }
  u16* const Pw = &Ps[w * 1024];
  const u16* rP = &Pw[c16 * 64];

  const int dbase = c16 - 16 * w - quad * 4;   // delta = dbase + t*64 + tcol*16 - r

  f32x4 acc[4];
#pragma unroll
  for (int dt = 0; dt < 4; ++dt) acc[dt] = f32x4{0.f, 0.f, 0.f, 0.f};
  float rsum[4] = {0.f, 0.f, 0.f, 0.f};

  for (int t = 0; t < 9; ++t) {
    __syncthreads();
    gll16(gK0, lK0); gll16(gK1, lK1);
    gll16(gV0, lV0); gll16(gV1, lV1);
    gK0 += 64 * 64; gK1 += 64 * 64; gV0 += 64; gV1 += 64;
    __syncthreads();

    // S = Q K^T ; mask+exp ; P -> LDS (per-wave, same-wave RAW via lgkmcnt)
#pragma unroll
    for (int tcol = 0; tcol < 4; ++tcol) {
      const bf16x8 bk0 = *(const bf16x8*)(rK[tcol] + off0);
      const bf16x8 bk1 = *(const bf16x8*)(rK[tcol] + off1);
      f32x4 s = f32x4{0.f, 0.f, 0.f, 0.f};
      s = MFMA16(aq0, bk0, s);
      s = MFMA16(aq1, bk1, s);
#pragma unroll
      for (int r = 0; r < 4; ++r) {
        const int delta = dbase + t * 64 + tcol * 16 - r;
        const float p = ((u32)delta < 512u) ? __expf(s[r] * 0.125f) : 0.f;
        rsum[r] += p;
        const int qi = quad * 4 + r;
        const int kc = tcol * 16 + c16;
        Pw[qi * 64 + (((kc >> 3) ^ (qi & 7)) * 8) + (kc & 7)] = f2b(p);
      }
    }

    // O += P V
    const bf16x8 ap0 = *(const bf16x8*)(rP + off0);
    const bf16x8 ap1 = *(const bf16x8*)(rP + off1);
#pragma unroll
    for (int dt = 0; dt < 4; ++dt) {
      const bf16x8 bv0 = *(const bf16x8*)(rV[dt] + off0);
      const bf16x8 bv1 = *(const bf16x8*)(rV[dt] + off1);
      acc[dt] = MFMA16(ap0, bv0, acc[dt]);
      acc[dt] = MFMA16(ap1, bv1, acc[dt]);
    }
  }

  // row-sum reduction across the 16 lanes holding each C-row
#pragma unroll
  for (int off = 1; off < 16; off <<= 1)
#pragma unroll
    for (int r = 0; r < 4; ++r)
      rsum[r] += __shfl_xor(rsum[r], off, 64);

  const int qp = qb0 + w * 16 + quad * 4;
#pragma unroll
  for (int r = 0; r < 4; ++r) {
    const float inv = 1.f / rsum[r];
#pragma unroll
    for (int dt = 0; dt < 4; ++dt)
      o[(long)(qp + r) * 1024 + h * 64 + dt * 16 + c16] = f2b(acc[dt][r] * inv);
  }
}

// ---------------------------------------------------------------------------
extern "C" void kernel_launch(void* const* d_in, const int* in_sizes, int n_in,
                              void* d_out, int out_size, void* d_ws, size_t ws_size,
                              hipStream_t stream)
{
  const float* x    = (const float*)d_in[0];   // (4096, 1024)
  const float* Wqkv = (const float*)d_in[1];   // (3072, 1024)
  const float* bqkv = (const float*)d_in[2];   // (3072,)
  const float* Wout = (const float*)d_in[3];   // (1024, 1024)
  const float* bout = (const float*)d_in[4];   // (1024,)
  float* out = (float*)d_out;                  // (4096, 1024)

  // ws layout (u16 elements): 52.4 MB total; xb|wqkvb|woutb contiguous
  u16* xb    = (u16*)d_ws;                         // 4096*1024
  u16* wqkvb = xb    + (size_t)4096 * 1024;        // 3072*1024
  u16* woutb = wqkvb + (size_t)3072 * 1024;        // 1024*1024
  u16* Qb    = woutb + (size_t)1024 * 1024;        // 4096*1024
  u16* Kp    = Qb    + (size_t)4096 * 1024;        // 16*4608*64
  u16* VTp   = Kp    + (size_t)16 * 4608 * 64;     // 16*64*4608
  u16* Vb    = VTp   + (size_t)16 * 4608 * 64;     // 4096*1024 (o aliases)
  u16* o     = Vb;                                 // Vb dead after repack_v

  cvt_all<<<1048576 / 256, 256, 0, stream>>>(x, Wqkv, Wout, xb);

  gemm_qkv<<<dim3(3072 / 128, 4096 / 64), 256, 0, stream>>>(
      xb, wqkvb, bqkv, Qb, Kp, Vb);
  repack_v<<<dim3(72, 16), 256, 0, stream>>>(Vb, Kp, VTp);
  swa_fused<<<1024, 256, 0, stream>>>(Qb, Kp, VTp, o);
  gemm_out<<<dim3(1024 / 64, 4096 / 64), 256, 0, stream>>>(o, woutb, bout, out);
}

// Round 10
// 161.107 us; speedup vs baseline: 1.1847x; 1.0241x over previous
//
#include <hip/hip_runtime.h>

// SlidingWindowAttention: B=1, S=4096, D=1024, H=16, d=64, WIN=512 (256 back / 255 fwd)
// Inputs/outputs FP32 storage (values bf16-rounded by harness).
//
// Pipeline (4 dispatches):
//   0) cvt_all   : x|Wqkv|Wout -> bf16 (contiguous ws) + zero Kp/VTp pad tiles
//   1) gemm_qkv  : 64x128 tile, BK=64, grid 1536; epilogue scatters Q->Qb,
//                  K->Kp (h,key+256,d), V->VTp (h,d,key+256) TRANSPOSED via
//                  8B packed stores (C-layout reg axis == key axis)
//   2) swa_fused : 64 q/block, 4 waves, flat grid 1024 with XCD-locality
//                  swizzle (XCD x <- heads {2x,2x+1}, qb ascending) so K/V
//                  stream through the per-XCD L2 once per head
//   3) gemm_out  : 64x64 tile, BK=64, grid 1024 -> fp32 out
//
// LDS swizzle (all kernels): row of 64 bf16 = 8 chunks of 8; chunk c of row r
// lives in slot c ^ (r & 7). Row stride 128 B == 0 mod 32 banks -> bank
// depends only on slot -> gll16 DMA writes and b128 fragment reads are
// conflict-free.

typedef __bf16 bf16x8 __attribute__((ext_vector_type(8)));
typedef float f32x4 __attribute__((ext_vector_type(4)));
typedef unsigned short u16;
typedef unsigned int u32;
typedef unsigned long long u64;

#define MFMA16(a, b, c) __builtin_amdgcn_mfma_f32_16x16x32_bf16(a, b, c, 0, 0, 0)

__device__ __forceinline__ u16 f2b(float f) {   // RNE f32 -> bf16 bits
  union { float f; u32 u; } x; x.f = f;
  u32 r = x.u + 0x7fffu + ((x.u >> 16) & 1u);
  return (u16)(r >> 16);
}

union U8x16 { int4 v; u16 u[8]; };

// async 16B global -> LDS (dest = wave-uniform base + lane*16, HW-generated)
__device__ __forceinline__ void gll16(const u16* g, u16* l) {
  __builtin_amdgcn_global_load_lds(
      (const __attribute__((address_space(1))) u16*)g,
      (__attribute__((address_space(3))) u16*)l, 16, 0, 0);
}

// ---------------------------------------------------------------------------
// fp32 -> bf16 for all three inputs (chunks 0..1048575, contiguous dst) plus
// pad-zeroing of Kp (chunks +0..65535) and VTp (chunks +65536..131071).
// Pad regions are disjoint from gemm_qkv's writes (keys [256,4352)) -> no
// ordering hazard beyond stream order.
// ---------------------------------------------------------------------------
__global__ void cvt_all(const float* __restrict__ x, const float* __restrict__ wqkv,
                        const float* __restrict__ wout, u16* __restrict__ dst,
                        u16* __restrict__ Kp, u16* __restrict__ VTp)
{
  const int i = blockIdx.x * blockDim.x + threadIdx.x;   // chunk index
  if (i < 1048576) {
    const float* src; int off;
    if (i < 524288)       { src = x;    off = i; }           // 4096*1024/8
    else if (i < 917504)  { src = wqkv; off = i - 524288; }  // +3072*1024/8
    else                  { src = wout; off = i - 917504; }  // +1024*1024/8
    const float4 a = ((const float4*)src)[off * 2];
    const float4 b = ((const float4*)src)[off * 2 + 1];
    U8x16 t;
    t.u[0] = f2b(a.x); t.u[1] = f2b(a.y); t.u[2] = f2b(a.z); t.u[3] = f2b(a.w);
    t.u[4] = f2b(b.x); t.u[5] = f2b(b.y); t.u[6] = f2b(b.z); t.u[7] = f2b(b.w);
    ((int4*)dst)[i] = t.v;
    return;
  }
  const int j = i - 1048576;
  const int4 z = {0, 0, 0, 0};
  if (j < 65536) {        // Kp pad rows: per h, rows [0,256) and [4352,4608)
    const int h = j >> 12, rem = j & 4095;
    const int row512 = rem >> 3, c8 = (rem & 7) * 8;
    const int row = (row512 < 256) ? row512 : (4096 + row512);
    *(int4*)(&Kp[((long)h * 4608 + row) * 64 + c8]) = z;
  } else {                // VTp pad cols: per h, keys [0,256) and [4352,4608)
    const int j2 = j - 65536;
    const int h = j2 >> 12, rem = j2 & 4095;
    const int d = rem >> 6, kc = rem & 63;
    const int key = (kc < 32) ? kc * 8 : (4096 + kc * 8);
    *(int4*)(&VTp[((long)h * 64 + d) * 4608 + key]) = z;
  }
}

// ---------------------------------------------------------------------------
// QKV GEMM: 64x128 tile, BK=64, grid (24, 64) = 1536 blocks
// (__launch_bounds__(256,6), LDS 24 KB). 2x2 waves, each 32x64:
// 2x4 MFMA tiles x 2 K-halves = 16 MFMA per barrier-round, 16 rounds.
// Epilogue scatters: Q (n<1024) -> Qb; K -> Kp (h, key+256, d);
// V -> VTp (h, d, key+256) TRANSPOSED: the C-layout reg axis (row=quad*4+r)
// is the key axis, so each lane packs its 4 keys into one 8B store.
// ---------------------------------------------------------------------------
__global__ __launch_bounds__(256, 6) void gemm_qkv(
    const u16* __restrict__ A, const u16* __restrict__ B,
    const float* __restrict__ bias,
    u16* __restrict__ Qb, u16* __restrict__ Kp, u16* __restrict__ VTp)
{
  __shared__ u16 As[64 * 64];    // 8 KB
  __shared__ u16 Bs[128 * 64];   // 16 KB

  const int K = 1024;
  const int tid  = threadIdx.x;
  const int lane = tid & 63;
  const int wave = tid >> 6;
  const int quad = lane >> 4;
  const int c16  = lane & 15;
  const int wr   = wave >> 1;            // M half (32 rows)
  const int wc   = wave & 1;             // N half (64 cols)
  const long m0 = (long)blockIdx.y * 64;
  const long n0 = (long)blockIdx.x * 128;

  const int rowo   = lane >> 3;
  const int schunk = (lane & 7) ^ rowo;
  const u16* gA0 = &A[(m0 + wave * 16 + rowo) * K + schunk * 8];
  const u16* gA1 = gA0 + 8 * K;
  const u16* gB0 = &B[(n0 + wave * 32 + rowo) * K + schunk * 8];
  const u16* gB1 = gB0 + 8 * K;
  const u16* gB2 = gB0 + 16 * K;
  const u16* gB3 = gB0 + 24 * K;
  u16* const lA0 = &As[(wave * 16) * 64];
  u16* const lA1 = lA0 + 8 * 64;
  u16* const lB0 = &Bs[(wave * 32) * 64];
  u16* const lB1 = lB0 + 8 * 64;
  u16* const lB2 = lB0 + 16 * 64;
  u16* const lB3 = lB0 + 24 * 64;

  const int rsw  = c16 & 7;
  const int off0 = (quad ^ rsw) * 8;
  const int off1 = ((4 + quad) ^ rsw) * 8;
  const u16* rA[2]; const u16* rB[4];
#pragma unroll
  for (int i = 0; i < 2; ++i) rA[i] = &As[(wr * 32 + i * 16 + c16) * 64];
#pragma unroll
  for (int j = 0; j < 4; ++j) rB[j] = &Bs[(wc * 64 + j * 16 + c16) * 64];

  f32x4 acc[2][4];
#pragma unroll
  for (int i = 0; i < 2; ++i)
#pragma unroll
    for (int j = 0; j < 4; ++j)
      acc[i][j] = f32x4{0.f, 0.f, 0.f, 0.f};

  for (int k0 = 0; k0 < K; k0 += 64) {
    __syncthreads();
    gll16(gA0, lA0); gll16(gA1, lA1);
    gll16(gB0, lB0); gll16(gB1, lB1); gll16(gB2, lB2); gll16(gB3, lB3);
    gA0 += 64; gA1 += 64; gB0 += 64; gB1 += 64; gB2 += 64; gB3 += 64;
    __syncthreads();

#pragma unroll
    for (int h = 0; h < 2; ++h) {
      const int off = h ? off1 : off0;
      bf16x8 af[2], bfr[4];
#pragma unroll
      for (int i = 0; i < 2; ++i) af[i]  = *(const bf16x8*)(rA[i] + off);
#pragma unroll
      for (int j = 0; j < 4; ++j) bfr[j] = *(const bf16x8*)(rB[j] + off);
#pragma unroll
      for (int i = 0; i < 2; ++i)
#pragma unroll
        for (int j = 0; j < 4; ++j)
          acc[i][j] = MFMA16(af[i], bfr[j], acc[i][j]);
    }
  }

  const int region = (int)(n0 >> 10);      // 0=Q, 1=K, 2=V (block-uniform)
#pragma unroll
  for (int i = 0; i < 2; ++i) {
    const long row0 = m0 + wr * 32 + i * 16 + quad * 4;
#pragma unroll
    for (int j = 0; j < 4; ++j) {
      const long col = n0 + wc * 64 + j * 16 + c16;
      const float bv = bias[col];
      if (region == 0) {
#pragma unroll
        for (int r = 0; r < 4; ++r)
          Qb[(row0 + r) * 1024 + col] = f2b(acc[i][j][r] + bv);
      } else if (region == 1) {
        const int n1 = (int)(col - 1024);
        const int h = n1 >> 6, d = n1 & 63;
#pragma unroll
        for (int r = 0; r < 4; ++r)
          Kp[((long)h * 4608 + row0 + r + 256) * 64 + d] = f2b(acc[i][j][r] + bv);
      } else {
        // V transposed: 4 consecutive keys (row0..row0+3) at fixed d -> 8B store
        const int n1 = (int)(col - 2048);
        const int h = n1 >> 6, d = n1 & 63;
        union { u16 q[4]; u64 ull; } pk;
#pragma unroll
        for (int r = 0; r < 4; ++r) pk.q[r] = f2b(acc[i][j][r] + bv);
        *(u64*)(&VTp[((long)h * 64 + d) * 4608 + 256 + row0]) = pk.ull;
      }
    }
  }
}

// ---------------------------------------------------------------------------
// Output GEMM: 64x64 tile, BK=64, grid (16, 64) = 1024 blocks = 4/CU.
// 2x2 waves, each 32x32: 2x2 MFMA tiles x 2 K-halves = 8 MFMA/round. fp32 out.
// ---------------------------------------------------------------------------
__global__ __launch_bounds__(256, 4) void gemm_out(
    const u16* __restrict__ A, const u16* __restrict__ B,
    const float* __restrict__ bias, float* __restrict__ C)
{
  __shared__ u16 As[64 * 64];    // 8 KB
  __shared__ u16 Bs[64 * 64];    // 8 KB

  const int K = 1024, N = 1024;
  const int tid  = threadIdx.x;
  const int lane = tid & 63;
  const int wave = tid >> 6;
  const int quad = lane >> 4;
  const int c16  = lane & 15;
  const int wr   = wave >> 1;
  const int wc   = wave & 1;
  const long m0 = (long)blockIdx.y * 64;
  const long n0 = (long)blockIdx.x * 64;

  const int rowo   = lane >> 3;
  const int schunk = (lane & 7) ^ rowo;
  const u16* gA0 = &A[(m0 + wave * 16 + rowo) * K + schunk * 8];
  const u16* gA1 = gA0 + 8 * K;
  const u16* gB0 = &B[(n0 + wave * 16 + rowo) * K + schunk * 8];
  const u16* gB1 = gB0 + 8 * K;
  u16* const lA0 = &As[(wave * 16) * 64];
  u16* const lA1 = lA0 + 8 * 64;
  u16* const lB0 = &Bs[(wave * 16) * 64];
  u16* const lB1 = lB0 + 8 * 64;

  const int rsw  = c16 & 7;
  const int off0 = (quad ^ rsw) * 8;
  const int off1 = ((4 + quad) ^ rsw) * 8;
  const u16* rA[2]; const u16* rB[2];
#pragma unroll
  for (int i = 0; i < 2; ++i) {
    rA[i] = &As[(wr * 32 + i * 16 + c16) * 64];
    rB[i] = &Bs[(wc * 32 + i * 16 + c16) * 64];
  }

  f32x4 acc[2][2];
#pragma unroll
  for (int i = 0; i < 2; ++i)
#pragma unroll
    for (int j = 0; j < 2; ++j)
      acc[i][j] = f32x4{0.f, 0.f, 0.f, 0.f};

  for (int k0 = 0; k0 < K; k0 += 64) {
    __syncthreads();
    gll16(gA0, lA0); gll16(gA1, lA1);
    gll16(gB0, lB0); gll16(gB1, lB1);
    gA0 += 64; gA1 += 64; gB0 += 64; gB1 += 64;
    __syncthreads();

#pragma unroll
    for (int h = 0; h < 2; ++h) {
      const int off = h ? off1 : off0;
      bf16x8 af[2], bfr[2];
#pragma unroll
      for (int i = 0; i < 2; ++i) af[i]  = *(const bf16x8*)(rA[i] + off);
#pragma unroll
      for (int j = 0; j < 2; ++j) bfr[j] = *(const bf16x8*)(rB[j] + off);
#pragma unroll
      for (int i = 0; i < 2; ++i)
#pragma unroll
        for (int j = 0; j < 2; ++j)
          acc[i][j] = MFMA16(af[i], bfr[j], acc[i][j]);
    }
  }

#pragma unroll
  for (int i = 0; i < 2; ++i) {
    const long row0 = m0 + wr * 32 + i * 16 + quad * 4;
#pragma unroll
    for (int j = 0; j < 2; ++j) {
      const long col = n0 + wc * 32 + j * 16 + c16;
      const float bv = bias[col];
#pragma unroll
      for (int r = 0; r < 4; ++r)
        C[(row0 + r) * N + col] = acc[i][j][r] + bv;
    }
  }
}

// ---------------------------------------------------------------------------
// Sliding-window flash attention. Flat grid 1024 blocks, 256 thr = 4 waves
// (4 blocks/CU, LDS 24 KB). XCD-locality swizzle: xcd = b & 7; XCD x gets
// heads {2x, 2x+1} with qb ascending -> the ~32 resident blocks per XCD share
// a sliding ~1k-key window (~0.8 MB K+V) in the 4 MB per-XCD L2.
// Wave w owns queries [qb0+16w, +16). 9 key tiles of 64 cover padded keys
// [qb0, qb0+576). Fixed-max softmax (|s| <~ 8 << 88): p = exp(s/8); pad keys
// (k=0,v=0) give p=1 in denominator, matching reference zero-padding.
// P per-wave in LDS (C-layout -> A-layout), slot-swizzled.
// ---------------------------------------------------------------------------
__global__ __launch_bounds__(256, 4) void swa_fused(
    const u16* __restrict__ Qb, const u16* __restrict__ Kp,
    const u16* __restrict__ VTp, u16* __restrict__ o)
{
  __shared__ u16 Ks[64 * 64];       // (key, d), slot-swizzled   8 KB
  __shared__ u16 Vs[64 * 64];       // (d, key), slot-swizzled   8 KB
  __shared__ u16 Ps[4 * 16 * 64];   // per-wave (q, key)          8 KB

  const int tid  = threadIdx.x;
  const int lane = tid & 63;
  const int w    = tid >> 6;
  const int quad = lane >> 4;
  const int c16  = lane & 15;

  // XCD-locality remap: b -> (h, qb0)
  const int b    = blockIdx.x;
  const int xcd  = b & 7;
  const int idx  = b >> 3;               // 0..127, ascending in launch order
  const int h    = xcd * 2 + (idx >> 6); // heads {2x, 2x+1}
  const int qb0  = (idx & 63) * 64;      // qb ascending within XCD

  const long qrow = qb0 + w * 16 + c16;
  const bf16x8 aq0 = *(const bf16x8*)(&Qb[qrow * 1024 + h * 64 + quad * 8]);
  const bf16x8 aq1 = *(const bf16x8*)(&Qb[qrow * 1024 + h * 64 + 32 + quad * 8]);

  const int rowo   = lane >> 3;
  const int gchunk = (lane & 7) ^ rowo;
  const u16* gK0 = &Kp[((long)h * 4608 + qb0 + w * 16 + rowo) * 64 + gchunk * 8];
  const u16* gK1 = gK0 + 8 * 64;
  const u16* gV0 = &VTp[((long)h * 64 + w * 16 + rowo) * 4608 + qb0 + gchunk * 8];
  const u16* gV1 = gV0 + 8 * 4608;
  u16* const lK0 = &Ks[(w * 16) * 64];
  u16* const lK1 = lK0 + 8 * 64;
  u16* const lV0 = &Vs[(w * 16) * 64];
  u16* const lV1 = lV0 + 8 * 64;

  const int rsw  = c16 & 7;
  const int off0 = (quad ^ rsw) * 8;
  const int off1 = ((4 + quad) ^ rsw) * 8;
  const u16* rK[4]; const u16* rV[4];
#pragma unroll
  for (int i = 0; i < 4; ++i) {
    rK[i] = &Ks[(i * 16 + c16) * 64];
    rV[i] = &Vs[(i * 16 + c16) * 64];
  }
  u16* const Pw = &Ps[w * 1024];
  const u16* rP = &Pw[c16 * 64];

  const int dbase = c16 - 16 * w - quad * 4;   // delta = dbase + t*64 + tcol*16 - r

  f32x4 acc[4];
#pragma unroll
  for (int dt = 0; dt < 4; ++dt) acc[dt] = f32x4{0.f, 0.f, 0.f, 0.f};
  float rsum[4] = {0.f, 0.f, 0.f, 0.f};

  for (int t = 0; t < 9; ++t) {
    __syncthreads();
    gll16(gK0, lK0); gll16(gK1, lK1);
    gll16(gV0, lV0); gll16(gV1, lV1);
    gK0 += 64 * 64; gK1 += 64 * 64; gV0 += 64; gV1 += 64;
    __syncthreads();

    // S = Q K^T ; mask+exp ; P -> LDS (per-wave, same-wave RAW via lgkmcnt)
#pragma unroll
    for (int tcol = 0; tcol < 4; ++tcol) {
      const bf16x8 bk0 = *(const bf16x8*)(rK[tcol] + off0);
      const bf16x8 bk1 = *(const bf16x8*)(rK[tcol] + off1);
      f32x4 s = f32x4{0.f, 0.f, 0.f, 0.f};
      s = MFMA16(aq0, bk0, s);
      s = MFMA16(aq1, bk1, s);
#pragma unroll
      for (int r = 0; r < 4; ++r) {
        const int delta = dbase + t * 64 + tcol * 16 - r;
        const float p = ((u32)delta < 512u) ? __expf(s[r] * 0.125f) : 0.f;
        rsum[r] += p;
        const int qi = quad * 4 + r;
        const int kc = tcol * 16 + c16;
        Pw[qi * 64 + (((kc >> 3) ^ (qi & 7)) * 8) + (kc & 7)] = f2b(p);
      }
    }

    // O += P V
    const bf16x8 ap0 = *(const bf16x8*)(rP + off0);
    const bf16x8 ap1 = *(const bf16x8*)(rP + off1);
#pragma unroll
    for (int dt = 0; dt < 4; ++dt) {
      const bf16x8 bv0 = *(const bf16x8*)(rV[dt] + off0);
      const bf16x8 bv1 = *(const bf16x8*)(rV[dt] + off1);
      acc[dt] = MFMA16(ap0, bv0, acc[dt]);
      acc[dt] = MFMA16(ap1, bv1, acc[dt]);
    }
  }

  // row-sum reduction across the 16 lanes holding each C-row
#pragma unroll
  for (int off = 1; off < 16; off <<= 1)
#pragma unroll
    for (int r = 0; r < 4; ++r)
      rsum[r] += __shfl_xor(rsum[r], off, 64);

  const int qp = qb0 + w * 16 + quad * 4;
#pragma unroll
  for (int r = 0; r < 4; ++r) {
    const float inv = 1.f / rsum[r];
#pragma unroll
    for (int dt = 0; dt < 4; ++dt)
      o[(long)(qp + r) * 1024 + h * 64 + dt * 16 + c16] = f2b(acc[dt][r] * inv);
  }
}

// ---------------------------------------------------------------------------
extern "C" void kernel_launch(void* const* d_in, const int* in_sizes, int n_in,
                              void* d_out, int out_size, void* d_ws, size_t ws_size,
                              hipStream_t stream)
{
  const float* x    = (const float*)d_in[0];   // (4096, 1024)
  const float* Wqkv = (const float*)d_in[1];   // (3072, 1024)
  const float* Wout = (const float*)d_in[3];   // (1024, 1024)
  const float* bqkv = (const float*)d_in[2];   // (3072,)
  const float* bout = (const float*)d_in[4];   // (1024,)
  float* out = (float*)d_out;                  // (4096, 1024)

  // ws layout (u16 elements); xb|wqkvb|woutb contiguous for cvt_all
  u16* xb    = (u16*)d_ws;                         // 4096*1024
  u16* wqkvb = xb    + (size_t)4096 * 1024;        // 3072*1024
  u16* woutb = wqkvb + (size_t)3072 * 1024;        // 1024*1024
  u16* Qb    = woutb + (size_t)1024 * 1024;        // 4096*1024
  u16* Kp    = Qb    + (size_t)4096 * 1024;        // 16*4608*64
  u16* VTp   = Kp    + (size_t)16 * 4608 * 64;     // 16*64*4608
  u16* o     = VTp   + (size_t)16 * 4608 * 64;     // 4096*1024

  // 1048576 convert chunks + 131072 pad-zero chunks
  cvt_all<<<(1048576 + 131072) / 256, 256, 0, stream>>>(x, Wqkv, Wout, xb, Kp, VTp);

  gemm_qkv<<<dim3(3072 / 128, 4096 / 64), 256, 0, stream>>>(
      xb, wqkvb, bqkv, Qb, Kp, VTp);
  swa_fused<<<1024, 256, 0, stream>>>(Qb, Kp, VTp, o);
  gemm_out<<<dim3(1024 / 64, 4096 / 64), 256, 0, stream>>>(o, woutb, bout, out);
}

// Round 11
// 156.729 us; speedup vs baseline: 1.2178x; 1.0279x over previous
//
#include <hip/hip_runtime.h>

// SlidingWindowAttention: B=1, S=4096, D=1024, H=16, d=64, WIN=512 (256 back / 255 fwd)
// Inputs/outputs FP32 storage (values bf16-rounded by harness).
//
// Pipeline (4 dispatches):
//   0) cvt_all   : x|Wqkv|Wout -> bf16 (contiguous ws) + zero Kp/VTp pad tiles
//   1) gemm_qkv  : 64x128 tile, BK=64, grid 1536; epilogue scatters Q->Qb,
//                  K->Kp (h,key+256,d) direct (L2-merged), V->VTp transposed
//                  via LDS re-tile -> fully coalesced 128B-run stores
//   2) swa_fused : 64 q/block, 4 waves, flat grid 1024 with XCD-locality
//                  swizzle (XCD x <- heads {2x,2x+1}, qb ascending)
//   3) gemm_out  : 64x64 tile, BK=64, grid 1024 -> fp32 out
//
// LDS swizzle (K-loop, all kernels): row of 64 bf16 = 8 chunks of 8; chunk c
// of row r lives in slot c ^ (r & 7). Row stride 128 B == 0 mod 32 banks ->
// gll16 DMA writes and b128 fragment reads are conflict-free.

typedef __bf16 bf16x8 __attribute__((ext_vector_type(8)));
typedef float f32x4 __attribute__((ext_vector_type(4)));
typedef unsigned short u16;
typedef unsigned int u32;

#define MFMA16(a, b, c) __builtin_amdgcn_mfma_f32_16x16x32_bf16(a, b, c, 0, 0, 0)

__device__ __forceinline__ u16 f2b(float f) {   // RNE f32 -> bf16 bits
  union { float f; u32 u; } x; x.f = f;
  u32 r = x.u + 0x7fffu + ((x.u >> 16) & 1u);
  return (u16)(r >> 16);
}

union U8x16 { int4 v; u16 u[8]; };

// async 16B global -> LDS (dest = wave-uniform base + lane*16, HW-generated)
__device__ __forceinline__ void gll16(const u16* g, u16* l) {
  __builtin_amdgcn_global_load_lds(
      (const __attribute__((address_space(1))) u16*)g,
      (__attribute__((address_space(3))) u16*)l, 16, 0, 0);
}

// ---------------------------------------------------------------------------
// fp32 -> bf16 for all three inputs (chunks 0..1048575, contiguous dst) plus
// pad-zeroing of Kp (chunks +0..65535) and VTp (chunks +65536..131071).
// ---------------------------------------------------------------------------
__global__ void cvt_all(const float* __restrict__ x, const float* __restrict__ wqkv,
                        const float* __restrict__ wout, u16* __restrict__ dst,
                        u16* __restrict__ Kp, u16* __restrict__ VTp)
{
  const int i = blockIdx.x * blockDim.x + threadIdx.x;   // chunk index
  if (i < 1048576) {
    const float* src; int off;
    if (i < 524288)       { src = x;    off = i; }           // 4096*1024/8
    else if (i < 917504)  { src = wqkv; off = i - 524288; }  // +3072*1024/8
    else                  { src = wout; off = i - 917504; }  // +1024*1024/8
    const float4 a = ((const float4*)src)[off * 2];
    const float4 b = ((const float4*)src)[off * 2 + 1];
    U8x16 t;
    t.u[0] = f2b(a.x); t.u[1] = f2b(a.y); t.u[2] = f2b(a.z); t.u[3] = f2b(a.w);
    t.u[4] = f2b(b.x); t.u[5] = f2b(b.y); t.u[6] = f2b(b.z); t.u[7] = f2b(b.w);
    ((int4*)dst)[i] = t.v;
    return;
  }
  const int j = i - 1048576;
  const int4 z = {0, 0, 0, 0};
  if (j < 65536) {        // Kp pad rows: per h, rows [0,256) and [4352,4608)
    const int h = j >> 12, rem = j & 4095;
    const int row512 = rem >> 3, c8 = (rem & 7) * 8;
    const int row = (row512 < 256) ? row512 : (4096 + row512);
    *(int4*)(&Kp[((long)h * 4608 + row) * 64 + c8]) = z;
  } else {                // VTp pad cols: per h, keys [0,256) and [4352,4608)
    const int j2 = j - 65536;
    const int h = j2 >> 12, rem = j2 & 4095;
    const int d = rem >> 6, kc = rem & 63;
    const int key = (kc < 32) ? kc * 8 : (4096 + kc * 8);
    *(int4*)(&VTp[((long)h * 64 + d) * 4608 + key]) = z;
  }
}

// ---------------------------------------------------------------------------
// QKV GEMM: 64x128 tile, BK=64, grid (24, 64) = 1536 blocks
// (__launch_bounds__(256,6), LDS 24 KB shared pool). 2x2 waves, each 32x64:
// 2x4 MFMA tiles x 2 K-halves = 16 MFMA per barrier-round, 16 rounds.
// Epilogue: Q -> Qb direct; K -> Kp direct (2B stores L2-merge to 128B runs);
// V -> LDS re-tile (col,key slot-swizzled) -> coalesced 16B stores to VTp.
// ---------------------------------------------------------------------------
__global__ __launch_bounds__(256, 6) void gemm_qkv(
    const u16* __restrict__ A, const u16* __restrict__ B,
    const float* __restrict__ bias,
    u16* __restrict__ Qb, u16* __restrict__ Kp, u16* __restrict__ VTp)
{
  __shared__ u16 smem[12288];    // 24 KB: As = smem[0..4095], Bs = smem[4096..]
  u16* const As = smem;          // 64 x 64
  u16* const Bs = smem + 4096;   // 128 x 64

  const int K = 1024;
  const int tid  = threadIdx.x;
  const int lane = tid & 63;
  const int wave = tid >> 6;
  const int quad = lane >> 4;
  const int c16  = lane & 15;
  const int wr   = wave >> 1;            // M half (32 rows)
  const int wc   = wave & 1;             // N half (64 cols)
  const long m0 = (long)blockIdx.y * 64;
  const long n0 = (long)blockIdx.x * 128;

  const int rowo   = lane >> 3;
  const int schunk = (lane & 7) ^ rowo;
  const u16* gA0 = &A[(m0 + wave * 16 + rowo) * K + schunk * 8];
  const u16* gA1 = gA0 + 8 * K;
  const u16* gB0 = &B[(n0 + wave * 32 + rowo) * K + schunk * 8];
  const u16* gB1 = gB0 + 8 * K;
  const u16* gB2 = gB0 + 16 * K;
  const u16* gB3 = gB0 + 24 * K;
  u16* const lA0 = &As[(wave * 16) * 64];
  u16* const lA1 = lA0 + 8 * 64;
  u16* const lB0 = &Bs[(wave * 32) * 64];
  u16* const lB1 = lB0 + 8 * 64;
  u16* const lB2 = lB0 + 16 * 64;
  u16* const lB3 = lB0 + 24 * 64;

  const int rsw  = c16 & 7;
  const int off0 = (quad ^ rsw) * 8;
  const int off1 = ((4 + quad) ^ rsw) * 8;
  const u16* rA[2]; const u16* rB[4];
#pragma unroll
  for (int i = 0; i < 2; ++i) rA[i] = &As[(wr * 32 + i * 16 + c16) * 64];
#pragma unroll
  for (int j = 0; j < 4; ++j) rB[j] = &Bs[(wc * 64 + j * 16 + c16) * 64];

  f32x4 acc[2][4];
#pragma unroll
  for (int i = 0; i < 2; ++i)
#pragma unroll
    for (int j = 0; j < 4; ++j)
      acc[i][j] = f32x4{0.f, 0.f, 0.f, 0.f};

  for (int k0 = 0; k0 < K; k0 += 64) {
    __syncthreads();
    gll16(gA0, lA0); gll16(gA1, lA1);
    gll16(gB0, lB0); gll16(gB1, lB1); gll16(gB2, lB2); gll16(gB3, lB3);
    gA0 += 64; gA1 += 64; gB0 += 64; gB1 += 64; gB2 += 64; gB3 += 64;
    __syncthreads();

#pragma unroll
    for (int h = 0; h < 2; ++h) {
      const int off = h ? off1 : off0;
      bf16x8 af[2], bfr[4];
#pragma unroll
      for (int i = 0; i < 2; ++i) af[i]  = *(const bf16x8*)(rA[i] + off);
#pragma unroll
      for (int j = 0; j < 4; ++j) bfr[j] = *(const bf16x8*)(rB[j] + off);
#pragma unroll
      for (int i = 0; i < 2; ++i)
#pragma unroll
        for (int j = 0; j < 4; ++j)
          acc[i][j] = MFMA16(af[i], bfr[j], acc[i][j]);
    }
  }

  const int region = (int)(n0 >> 10);      // 0=Q, 1=K, 2=V (block-uniform)
  if (region == 2) {
    // V: re-tile through LDS (transposed, slot-swizzled), then coalesced
    // 16B stores: 8 consecutive lanes cover one (h,d) row's 64 keys = 128 B.
    __syncthreads();                        // staging reads of smem complete
    u16* const Ts = smem;                   // 128 cols x 64 keys (16 KB)
#pragma unroll
    for (int i = 0; i < 2; ++i)
#pragma unroll
      for (int j = 0; j < 4; ++j) {
        const int col = wc * 64 + j * 16 + c16;
        const float bv = bias[n0 + col];
#pragma unroll
        for (int r = 0; r < 4; ++r) {
          const int key  = wr * 32 + i * 16 + quad * 4 + r;   // block-local
          const int slot = (key >> 3) ^ (col & 7);
          Ts[col * 64 + slot * 8 + (key & 7)] = f2b(acc[i][j][r] + bv);
        }
      }
    __syncthreads();
    const int base_n1 = (int)(n0 - 2048);
#pragma unroll
    for (int k = 0; k < 4; ++k) {
      const int idx  = k * 256 + tid;
      const int col  = idx >> 3, kc = idx & 7;
      const int slot = kc ^ (col & 7);
      const int4 v = *(const int4*)(&Ts[col * 64 + slot * 8]);
      const int n1 = base_n1 + col;
      const int h = n1 >> 6, d = n1 & 63;
      *(int4*)(&VTp[((long)h * 64 + d) * 4608 + 256 + m0 + kc * 8]) = v;
    }
    return;
  }

#pragma unroll
  for (int i = 0; i < 2; ++i) {
    const long row0 = m0 + wr * 32 + i * 16 + quad * 4;
#pragma unroll
    for (int j = 0; j < 4; ++j) {
      const long col = n0 + wc * 64 + j * 16 + c16;
      const float bv = bias[col];
      if (region == 0) {
#pragma unroll
        for (int r = 0; r < 4; ++r)
          Qb[(row0 + r) * 1024 + col] = f2b(acc[i][j][r] + bv);
      } else {
        const int n1 = (int)(col - 1024);
        const int h = n1 >> 6, d = n1 & 63;
#pragma unroll
        for (int r = 0; r < 4; ++r)
          Kp[((long)h * 4608 + row0 + r + 256) * 64 + d] = f2b(acc[i][j][r] + bv);
      }
    }
  }
}

// ---------------------------------------------------------------------------
// Output GEMM: 64x64 tile, BK=64, grid (16, 64) = 1024 blocks = 4/CU.
// 2x2 waves, each 32x32: 2x2 MFMA tiles x 2 K-halves = 8 MFMA/round. fp32 out.
// ---------------------------------------------------------------------------
__global__ __launch_bounds__(256, 4) void gemm_out(
    const u16* __restrict__ A, const u16* __restrict__ B,
    const float* __restrict__ bias, float* __restrict__ C)
{
  __shared__ u16 As[64 * 64];    // 8 KB
  __shared__ u16 Bs[64 * 64];    // 8 KB

  const int K = 1024, N = 1024;
  const int tid  = threadIdx.x;
  const int lane = tid & 63;
  const int wave = tid >> 6;
  const int quad = lane >> 4;
  const int c16  = lane & 15;
  const int wr   = wave >> 1;
  const int wc   = wave & 1;
  const long m0 = (long)blockIdx.y * 64;
  const long n0 = (long)blockIdx.x * 64;

  const int rowo   = lane >> 3;
  const int schunk = (lane & 7) ^ rowo;
  const u16* gA0 = &A[(m0 + wave * 16 + rowo) * K + schunk * 8];
  const u16* gA1 = gA0 + 8 * K;
  const u16* gB0 = &B[(n0 + wave * 16 + rowo) * K + schunk * 8];
  const u16* gB1 = gB0 + 8 * K;
  u16* const lA0 = &As[(wave * 16) * 64];
  u16* const lA1 = lA0 + 8 * 64;
  u16* const lB0 = &Bs[(wave * 16) * 64];
  u16* const lB1 = lB0 + 8 * 64;

  const int rsw  = c16 & 7;
  const int off0 = (quad ^ rsw) * 8;
  const int off1 = ((4 + quad) ^ rsw) * 8;
  const u16* rA[2]; const u16* rB[2];
#pragma unroll
  for (int i = 0; i < 2; ++i) {
    rA[i] = &As[(wr * 32 + i * 16 + c16) * 64];
    rB[i] = &Bs[(wc * 32 + i * 16 + c16) * 64];
  }

  f32x4 acc[2][2];
#pragma unroll
  for (int i = 0; i < 2; ++i)
#pragma unroll
    for (int j = 0; j < 2; ++j)
      acc[i][j] = f32x4{0.f, 0.f, 0.f, 0.f};

  for (int k0 = 0; k0 < K; k0 += 64) {
    __syncthreads();
    gll16(gA0, lA0); gll16(gA1, lA1);
    gll16(gB0, lB0); gll16(gB1, lB1);
    gA0 += 64; gA1 += 64; gB0 += 64; gB1 += 64;
    __syncthreads();

#pragma unroll
    for (int h = 0; h < 2; ++h) {
      const int off = h ? off1 : off0;
      bf16x8 af[2], bfr[2];
#pragma unroll
      for (int i = 0; i < 2; ++i) af[i]  = *(const bf16x8*)(rA[i] + off);
#pragma unroll
      for (int j = 0; j < 2; ++j) bfr[j] = *(const bf16x8*)(rB[j] + off);
#pragma unroll
      for (int i = 0; i < 2; ++i)
#pragma unroll
        for (int j = 0; j < 2; ++j)
          acc[i][j] = MFMA16(af[i], bfr[j], acc[i][j]);
    }
  }

#pragma unroll
  for (int i = 0; i < 2; ++i) {
    const long row0 = m0 + wr * 32 + i * 16 + quad * 4;
#pragma unroll
    for (int j = 0; j < 2; ++j) {
      const long col = n0 + wc * 32 + j * 16 + c16;
      const float bv = bias[col];
#pragma unroll
      for (int r = 0; r < 4; ++r)
        C[(row0 + r) * N + col] = acc[i][j][r] + bv;
    }
  }
}

// ---------------------------------------------------------------------------
// Sliding-window flash attention. Flat grid 1024 blocks, 256 thr = 4 waves
// (4 blocks/CU, LDS 24 KB). XCD-locality swizzle: xcd = b & 7; XCD x gets
// heads {2x, 2x+1} with qb ascending -> resident blocks per XCD share a
// sliding ~1k-key window (~0.8 MB K+V) in the 4 MB per-XCD L2.
// Wave w owns queries [qb0+16w, +16). 9 key tiles of 64 cover padded keys
// [qb0, qb0+576). Fixed-max softmax (|s| <~ 8 << 88): p = exp(s/8); pad keys
// (k=0,v=0) give p=1 in denominator, matching reference zero-padding.
// P per-wave in LDS (C-layout -> A-layout), slot-swizzled.
// ---------------------------------------------------------------------------
__global__ __launch_bounds__(256, 4) void swa_fused(
    const u16* __restrict__ Qb, const u16* __restrict__ Kp,
    const u16* __restrict__ VTp, u16* __restrict__ o)
{
  __shared__ u16 Ks[64 * 64];       // (key, d), slot-swizzled   8 KB
  __shared__ u16 Vs[64 * 64];       // (d, key), slot-swizzled   8 KB
  __shared__ u16 Ps[4 * 16 * 64];   // per-wave (q, key)          8 KB

  const int tid  = threadIdx.x;
  const int lane = tid & 63;
  const int w    = tid >> 6;
  const int quad = lane >> 4;
  const int c16  = lane & 15;

  // XCD-locality remap: b -> (h, qb0)
  const int b    = blockIdx.x;
  const int xcd  = b & 7;
  const int idx  = b >> 3;               // 0..127, ascending in launch order
  const int h    = xcd * 2 + (idx >> 6); // heads {2x, 2x+1}
  const int qb0  = (idx & 63) * 64;      // qb ascending within XCD

  const long qrow = qb0 + w * 16 + c16;
  const bf16x8 aq0 = *(const bf16x8*)(&Qb[qrow * 1024 + h * 64 + quad * 8]);
  const bf16x8 aq1 = *(const bf16x8*)(&Qb[qrow * 1024 + h * 64 + 32 + quad * 8]);

  const int rowo   = lane >> 3;
  const int gchunk = (lane & 7) ^ rowo;
  const u16* gK0 = &Kp[((long)h * 4608 + qb0 + w * 16 + rowo) * 64 + gchunk * 8];
  const u16* gK1 = gK0 + 8 * 64;
  const u16* gV0 = &VTp[((long)h * 64 + w * 16 + rowo) * 4608 + qb0 + gchunk * 8];
  const u16* gV1 = gV0 + 8 * 4608;
  u16* const lK0 = &Ks[(w * 16) * 64];
  u16* const lK1 = lK0 + 8 * 64;
  u16* const lV0 = &Vs[(w * 16) * 64];
  u16* const lV1 = lV0 + 8 * 64;

  const int rsw  = c16 & 7;
  const int off0 = (quad ^ rsw) * 8;
  const int off1 = ((4 + quad) ^ rsw) * 8;
  const u16* rK[4]; const u16* rV[4];
#pragma unroll
  for (int i = 0; i < 4; ++i) {
    rK[i] = &Ks[(i * 16 + c16) * 64];
    rV[i] = &Vs[(i * 16 + c16) * 64];
  }
  u16* const Pw = &Ps[w * 1024];
  const u16* rP = &Pw[c16 * 64];

  const int dbase = c16 - 16 * w - quad * 4;   // delta = dbase + t*64 + tcol*16 - r

  f32x4 acc[4];
#pragma unroll
  for (int dt = 0; dt < 4; ++dt) acc[dt] = f32x4{0.f, 0.f, 0.f, 0.f};
  float rsum[4] = {0.f, 0.f, 0.f, 0.f};

  for (int t = 0; t < 9; ++t) {
    __syncthreads();
    gll16(gK0, lK0); gll16(gK1, lK1);
    gll16(gV0, lV0); gll16(gV1, lV1);
    gK0 += 64 * 64; gK1 += 64 * 64; gV0 += 64; gV1 += 64;
    __syncthreads();

    // S = Q K^T ; mask+exp ; P -> LDS (per-wave, same-wave RAW via lgkmcnt)
#pragma unroll
    for (int tcol = 0; tcol < 4; ++tcol) {
      const bf16x8 bk0 = *(const bf16x8*)(rK[tcol] + off0);
      const bf16x8 bk1 = *(const bf16x8*)(rK[tcol] + off1);
      f32x4 s = f32x4{0.f, 0.f, 0.f, 0.f};
      s = MFMA16(aq0, bk0, s);
      s = MFMA16(aq1, bk1, s);
#pragma unroll
      for (int r = 0; r < 4; ++r) {
        const int delta = dbase + t * 64 + tcol * 16 - r;
        const float p = ((u32)delta < 512u) ? __expf(s[r] * 0.125f) : 0.f;
        rsum[r] += p;
        const int qi = quad * 4 + r;
        const int kc = tcol * 16 + c16;
        Pw[qi * 64 + (((kc >> 3) ^ (qi & 7)) * 8) + (kc & 7)] = f2b(p);
      }
    }

    // O += P V
    const bf16x8 ap0 = *(const bf16x8*)(rP + off0);
    const bf16x8 ap1 = *(const bf16x8*)(rP + off1);
#pragma unroll
    for (int dt = 0; dt < 4; ++dt) {
      const bf16x8 bv0 = *(const bf16x8*)(rV[dt] + off0);
      const bf16x8 bv1 = *(const bf16x8*)(rV[dt] + off1);
      acc[dt] = MFMA16(ap0, bv0, acc[dt]);
      acc[dt] = MFMA16(ap1, bv1, acc[dt]);
    }
  }

  // row-sum reduction across the 16 lanes holding each C-row
#pragma unroll
  for (int off = 1; off < 16; off <<= 1)
#pragma unroll
    for (int r = 0; r < 4; ++r)
      rsum[r] += __shfl_xor(rsum[r], off, 64);

  const int qp = qb0 + w * 16 + quad * 4;
#pragma unroll
  for (int r = 0; r < 4; ++r) {
    const float inv = 1.f / rsum[r];
#pragma unroll
    for (int dt = 0; dt < 4; ++dt)
      o[(long)(qp + r) * 1024 + h * 64 + dt * 16 + c16] = f2b(acc[dt][r] * inv);
  }
}

// ---------------------------------------------------------------------------
extern "C" void kernel_launch(void* const* d_in, const int* in_sizes, int n_in,
                              void* d_out, int out_size, void* d_ws, size_t ws_size,
                              hipStream_t stream)
{
  const float* x    = (const float*)d_in[0];   // (4096, 1024)
  const float* Wqkv = (const float*)d_in[1];   // (3072, 1024)
  const float* bqkv = (const float*)d_in[2];   // (3072,)
  const float* Wout = (const float*)d_in[3];   // (1024, 1024)
  const float* bout = (const float*)d_in[4];   // (1024,)
  float* out = (float*)d_out;                  // (4096, 1024)

  // ws layout (u16 elements); xb|wqkvb|woutb contiguous for cvt_all
  u16* xb    = (u16*)d_ws;                         // 4096*1024
  u16* wqkvb = xb    + (size_t)4096 * 1024;        // 3072*1024
  u16* woutb = wqkvb + (size_t)3072 * 1024;        // 1024*1024
  u16* Qb    = woutb + (size_t)1024 * 1024;        // 4096*1024
  u16* Kp    = Qb    + (size_t)4096 * 1024;        // 16*4608*64
  u16* VTp   = Kp    + (size_t)16 * 4608 * 64;     // 16*64*4608
  u16* o     = VTp   + (size_t)16 * 4608 * 64;     // 4096*1024

  // 1048576 convert chunks + 131072 pad-zero chunks
  cvt_all<<<(1048576 + 131072) / 256, 256, 0, stream>>>(x, Wqkv, Wout, xb, Kp, VTp);

  gemm_qkv<<<dim3(3072 / 128, 4096 / 64), 256, 0, stream>>>(
      xb, wqkvb, bqkv, Qb, Kp, VTp);
  swa_fused<<<1024, 256, 0, stream>>>(Qb, Kp, VTp, o);
  gemm_out<<<dim3(1024 / 64, 4096 / 64), 256, 0, stream>>>(o, woutb, bout, out);
}

// Round 13
// 154.611 us; speedup vs baseline: 1.2345x; 1.0137x over previous
//
#include <hip/hip_runtime.h>

// SlidingWindowAttention: B=1, S=4096, D=1024, H=16, d=64, WIN=512 (256 back / 255 fwd)
// Inputs/outputs FP32 storage (values bf16-rounded by harness).
//
// Pipeline (4 dispatches):
//   0) cvt_all   : x|Wqkv|Wout -> bf16 (contiguous ws) + zero Kp/VTp pad tiles
//   1) gemm_qkv  : 64x128 tile, BK=64, grid 1536; epilogue scatters
//                  Q*0.125 -> Qb (score scale folded in, exact pow2),
//                  K -> Kp (h,key+256,d), V -> VTp transposed via LDS re-tile
//   2) swa_fused : 64 q/block, 4 waves, flat grid 1024, XCD-locality swizzle;
//                  128-key staging tiles (5 barrier rounds), two 64-key
//                  half-passes per tile reusing the per-wave P buffer
//   3) gemm_out  : 64x64 tile, BK=64, grid 1024 -> fp32 out
//
// R12 bug fixed here: V staging now stores slot = chunk ^ (d & 15) (per-gll16
// XOR term 4k + lane>>4), matching the read side. R12 used a single XOR term
// (d & 3) -> scrambled V for (d&15) >= 4.

typedef __bf16 bf16x8 __attribute__((ext_vector_type(8)));
typedef float f32x4 __attribute__((ext_vector_type(4)));
typedef unsigned short u16;
typedef unsigned int u32;

#define MFMA16(a, b, c) __builtin_amdgcn_mfma_f32_16x16x32_bf16(a, b, c, 0, 0, 0)

__device__ __forceinline__ u16 f2b(float f) {   // RNE f32 -> bf16 bits
  union { float f; u32 u; } x; x.f = f;
  u32 r = x.u + 0x7fffu + ((x.u >> 16) & 1u);
  return (u16)(r >> 16);
}

union U8x16 { int4 v; u16 u[8]; };

// async 16B global -> LDS (dest = wave-uniform base + lane*16, HW-generated)
__device__ __forceinline__ void gll16(const u16* g, u16* l) {
  __builtin_amdgcn_global_load_lds(
      (const __attribute__((address_space(1))) u16*)g,
      (__attribute__((address_space(3))) u16*)l, 16, 0, 0);
}

// ---------------------------------------------------------------------------
// fp32 -> bf16 for all three inputs (chunks 0..1048575, contiguous dst) plus
// pad-zeroing of Kp (chunks +0..65535) and VTp (chunks +65536..131071).
// ---------------------------------------------------------------------------
__global__ void cvt_all(const float* __restrict__ x, const float* __restrict__ wqkv,
                        const float* __restrict__ wout, u16* __restrict__ dst,
                        u16* __restrict__ Kp, u16* __restrict__ VTp)
{
  const int i = blockIdx.x * blockDim.x + threadIdx.x;   // chunk index
  if (i < 1048576) {
    const float* src; int off;
    if (i < 524288)       { src = x;    off = i; }           // 4096*1024/8
    else if (i < 917504)  { src = wqkv; off = i - 524288; }  // +3072*1024/8
    else                  { src = wout; off = i - 917504; }  // +1024*1024/8
    const float4 a = ((const float4*)src)[off * 2];
    const float4 b = ((const float4*)src)[off * 2 + 1];
    U8x16 t;
    t.u[0] = f2b(a.x); t.u[1] = f2b(a.y); t.u[2] = f2b(a.z); t.u[3] = f2b(a.w);
    t.u[4] = f2b(b.x); t.u[5] = f2b(b.y); t.u[6] = f2b(b.z); t.u[7] = f2b(b.w);
    ((int4*)dst)[i] = t.v;
    return;
  }
  const int j = i - 1048576;
  const int4 z = {0, 0, 0, 0};
  if (j < 65536) {        // Kp pad rows: per h, rows [0,256) and [4352,4608)
    const int h = j >> 12, rem = j & 4095;
    const int row512 = rem >> 3, c8 = (rem & 7) * 8;
    const int row = (row512 < 256) ? row512 : (4096 + row512);
    *(int4*)(&Kp[((long)h * 4608 + row) * 64 + c8]) = z;
  } else {                // VTp pad cols: per h, keys [0,256) and [4352,4608)
    const int j2 = j - 65536;
    const int h = j2 >> 12, rem = j2 & 4095;
    const int d = rem >> 6, kc = rem & 63;
    const int key = (kc < 32) ? kc * 8 : (4096 + kc * 8);
    *(int4*)(&VTp[((long)h * 64 + d) * 4608 + key]) = z;
  }
}

// ---------------------------------------------------------------------------
// QKV GEMM: 64x128 tile, BK=64, grid (24, 64) = 1536 blocks
// (__launch_bounds__(256,6), LDS 24 KB shared pool). 2x2 waves, each 32x64:
// 2x4 MFMA tiles x 2 K-halves = 16 MFMA per barrier-round, 16 rounds.
// Epilogue: Q -> Qb * 0.125 (exact pow2; score scale folded out of swa);
// K -> Kp direct (2B stores L2-merge to 128B runs);
// V -> LDS re-tile (col,key slot-swizzled) -> coalesced 16B stores to VTp.
// ---------------------------------------------------------------------------
__global__ __launch_bounds__(256, 6) void gemm_qkv(
    const u16* __restrict__ A, const u16* __restrict__ B,
    const float* __restrict__ bias,
    u16* __restrict__ Qb, u16* __restrict__ Kp, u16* __restrict__ VTp)
{
  __shared__ u16 smem[12288];    // 24 KB: As = smem[0..4095], Bs = smem[4096..]
  u16* const As = smem;          // 64 x 64
  u16* const Bs = smem + 4096;   // 128 x 64

  const int K = 1024;
  const int tid  = threadIdx.x;
  const int lane = tid & 63;
  const int wave = tid >> 6;
  const int quad = lane >> 4;
  const int c16  = lane & 15;
  const int wr   = wave >> 1;            // M half (32 rows)
  const int wc   = wave & 1;             // N half (64 cols)
  const long m0 = (long)blockIdx.y * 64;
  const long n0 = (long)blockIdx.x * 128;

  const int rowo   = lane >> 3;
  const int schunk = (lane & 7) ^ rowo;
  const u16* gA0 = &A[(m0 + wave * 16 + rowo) * K + schunk * 8];
  const u16* gA1 = gA0 + 8 * K;
  const u16* gB0 = &B[(n0 + wave * 32 + rowo) * K + schunk * 8];
  const u16* gB1 = gB0 + 8 * K;
  const u16* gB2 = gB0 + 16 * K;
  const u16* gB3 = gB0 + 24 * K;
  u16* const lA0 = &As[(wave * 16) * 64];
  u16* const lA1 = lA0 + 8 * 64;
  u16* const lB0 = &Bs[(wave * 32) * 64];
  u16* const lB1 = lB0 + 8 * 64;
  u16* const lB2 = lB0 + 16 * 64;
  u16* const lB3 = lB0 + 24 * 64;

  const int rsw  = c16 & 7;
  const int off0 = (quad ^ rsw) * 8;
  const int off1 = ((4 + quad) ^ rsw) * 8;
  const u16* rA[2]; const u16* rB[4];
#pragma unroll
  for (int i = 0; i < 2; ++i) rA[i] = &As[(wr * 32 + i * 16 + c16) * 64];
#pragma unroll
  for (int j = 0; j < 4; ++j) rB[j] = &Bs[(wc * 64 + j * 16 + c16) * 64];

  f32x4 acc[2][4];
#pragma unroll
  for (int i = 0; i < 2; ++i)
#pragma unroll
    for (int j = 0; j < 4; ++j)
      acc[i][j] = f32x4{0.f, 0.f, 0.f, 0.f};

  for (int k0 = 0; k0 < K; k0 += 64) {
    __syncthreads();
    gll16(gA0, lA0); gll16(gA1, lA1);
    gll16(gB0, lB0); gll16(gB1, lB1); gll16(gB2, lB2); gll16(gB3, lB3);
    gA0 += 64; gA1 += 64; gB0 += 64; gB1 += 64; gB2 += 64; gB3 += 64;
    __syncthreads();

#pragma unroll
    for (int h = 0; h < 2; ++h) {
      const int off = h ? off1 : off0;
      bf16x8 af[2], bfr[4];
#pragma unroll
      for (int i = 0; i < 2; ++i) af[i]  = *(const bf16x8*)(rA[i] + off);
#pragma unroll
      for (int j = 0; j < 4; ++j) bfr[j] = *(const bf16x8*)(rB[j] + off);
#pragma unroll
      for (int i = 0; i < 2; ++i)
#pragma unroll
        for (int j = 0; j < 4; ++j)
          acc[i][j] = MFMA16(af[i], bfr[j], acc[i][j]);
    }
  }

  const int region = (int)(n0 >> 10);      // 0=Q, 1=K, 2=V (block-uniform)
  if (region == 2) {
    // V: re-tile through LDS (transposed, slot-swizzled), then coalesced
    // 16B stores: 8 consecutive lanes cover one (h,d) row's 64 keys = 128 B.
    __syncthreads();                        // staging reads of smem complete
    u16* const Ts = smem;                   // 128 cols x 64 keys (16 KB)
#pragma unroll
    for (int i = 0; i < 2; ++i)
#pragma unroll
      for (int j = 0; j < 4; ++j) {
        const int col = wc * 64 + j * 16 + c16;
        const float bv = bias[n0 + col];
#pragma unroll
        for (int r = 0; r < 4; ++r) {
          const int key  = wr * 32 + i * 16 + quad * 4 + r;   // block-local
          const int slot = (key >> 3) ^ (col & 7);
          Ts[col * 64 + slot * 8 + (key & 7)] = f2b(acc[i][j][r] + bv);
        }
      }
    __syncthreads();
    const int base_n1 = (int)(n0 - 2048);
#pragma unroll
    for (int k = 0; k < 4; ++k) {
      const int idx  = k * 256 + tid;
      const int col  = idx >> 3, kc = idx & 7;
      const int slot = kc ^ (col & 7);
      const int4 v = *(const int4*)(&Ts[col * 64 + slot * 8]);
      const int n1 = base_n1 + col;
      const int h = n1 >> 6, d = n1 & 63;
      *(int4*)(&VTp[((long)h * 64 + d) * 4608 + 256 + m0 + kc * 8]) = v;
    }
    return;
  }

#pragma unroll
  for (int i = 0; i < 2; ++i) {
    const long row0 = m0 + wr * 32 + i * 16 + quad * 4;
#pragma unroll
    for (int j = 0; j < 4; ++j) {
      const long col = n0 + wc * 64 + j * 16 + c16;
      const float bv = bias[col];
      if (region == 0) {
        // fold the 1/sqrt(d)=0.125 score scale into Q (exact pow2 scaling)
#pragma unroll
        for (int r = 0; r < 4; ++r)
          Qb[(row0 + r) * 1024 + col] = f2b((acc[i][j][r] + bv) * 0.125f);
      } else {
        const int n1 = (int)(col - 1024);
        const int h = n1 >> 6, d = n1 & 63;
#pragma unroll
        for (int r = 0; r < 4; ++r)
          Kp[((long)h * 4608 + row0 + r + 256) * 64 + d] = f2b(acc[i][j][r] + bv);
      }
    }
  }
}

// ---------------------------------------------------------------------------
// Output GEMM: 64x64 tile, BK=64, grid (16, 64) = 1024 blocks = 4/CU.
// 2x2 waves, each 32x32: 2x2 MFMA tiles x 2 K-halves = 8 MFMA/round. fp32 out.
// ---------------------------------------------------------------------------
__global__ __launch_bounds__(256, 4) void gemm_out(
    const u16* __restrict__ A, const u16* __restrict__ B,
    const float* __restrict__ bias, float* __restrict__ C)
{
  __shared__ u16 As[64 * 64];    // 8 KB
  __shared__ u16 Bs[64 * 64];    // 8 KB

  const int K = 1024, N = 1024;
  const int tid  = threadIdx.x;
  const int lane = tid & 63;
  const int wave = tid >> 6;
  const int quad = lane >> 4;
  const int c16  = lane & 15;
  const int wr   = wave >> 1;
  const int wc   = wave & 1;
  const long m0 = (long)blockIdx.y * 64;
  const long n0 = (long)blockIdx.x * 64;

  const int rowo   = lane >> 3;
  const int schunk = (lane & 7) ^ rowo;
  const u16* gA0 = &A[(m0 + wave * 16 + rowo) * K + schunk * 8];
  const u16* gA1 = gA0 + 8 * K;
  const u16* gB0 = &B[(n0 + wave * 16 + rowo) * K + schunk * 8];
  const u16* gB1 = gB0 + 8 * K;
  u16* const lA0 = &As[(wave * 16) * 64];
  u16* const lA1 = lA0 + 8 * 64;
  u16* const lB0 = &Bs[(wave * 16) * 64];
  u16* const lB1 = lB0 + 8 * 64;

  const int rsw  = c16 & 7;
  const int off0 = (quad ^ rsw) * 8;
  const int off1 = ((4 + quad) ^ rsw) * 8;
  const u16* rA[2]; const u16* rB[2];
#pragma unroll
  for (int i = 0; i < 2; ++i) {
    rA[i] = &As[(wr * 32 + i * 16 + c16) * 64];
    rB[i] = &Bs[(wc * 32 + i * 16 + c16) * 64];
  }

  f32x4 acc[2][2];
#pragma unroll
  for (int i = 0; i < 2; ++i)
#pragma unroll
    for (int j = 0; j < 2; ++j)
      acc[i][j] = f32x4{0.f, 0.f, 0.f, 0.f};

  for (int k0 = 0; k0 < K; k0 += 64) {
    __syncthreads();
    gll16(gA0, lA0); gll16(gA1, lA1);
    gll16(gB0, lB0); gll16(gB1, lB1);
    gA0 += 64; gA1 += 64; gB0 += 64; gB1 += 64;
    __syncthreads();

#pragma unroll
    for (int h = 0; h < 2; ++h) {
      const int off = h ? off1 : off0;
      bf16x8 af[2], bfr[2];
#pragma unroll
      for (int i = 0; i < 2; ++i) af[i]  = *(const bf16x8*)(rA[i] + off);
#pragma unroll
      for (int j = 0; j < 2; ++j) bfr[j] = *(const bf16x8*)(rB[j] + off);
#pragma unroll
      for (int i = 0; i < 2; ++i)
#pragma unroll
        for (int j = 0; j < 2; ++j)
          acc[i][j] = MFMA16(af[i], bfr[j], acc[i][j]);
    }
  }

#pragma unroll
  for (int i = 0; i < 2; ++i) {
    const long row0 = m0 + wr * 32 + i * 16 + quad * 4;
#pragma unroll
    for (int j = 0; j < 2; ++j) {
      const long col = n0 + wc * 32 + j * 16 + c16;
      const float bv = bias[col];
#pragma unroll
      for (int r = 0; r < 4; ++r)
        C[(row0 + r) * N + col] = acc[i][j][r] + bv;
    }
  }
}

// ---------------------------------------------------------------------------
// Sliding-window flash attention. Flat grid 1024 blocks, 256 thr = 4 waves,
// LDS 40 KB -> exactly 4 blocks/CU. XCD-locality swizzle: xcd = b & 7; XCD x
// gets heads {2x, 2x+1} with qb ascending (sliding K/V window lives in the
// per-XCD L2).
// 128-key staging tiles: 5 barrier rounds cover padded keys [qb0, qb0+640).
// Each tile is consumed in two 64-key half-passes that reuse the per-wave
// P buffer (same-wave in-order DS pipeline). Half-pass 9 (t=4,hf=1) is fully
// out-of-band and skipped uniformly. Staged-but-unused rows may read past
// key 4608 into adjacent ws regions -- allocated, never consumed.
// Q arrives pre-scaled by 0.125 -> p = exp(s) directly.
// Ks: (key,d) rows of 8 chunks, slot = chunk ^ (key&7).
// Vs: (d,key) rows of 16 chunks, slot = chunk ^ (d&15)  [per-gll16 XOR term
// 4k + lane>>4 -- the R12 bug was using lane>>4 only]. Both read patterns
// are 2-way bank aliasing = free.
// ---------------------------------------------------------------------------
__global__ __launch_bounds__(256, 4) void swa_fused(
    const u16* __restrict__ Qb, const u16* __restrict__ Kp,
    const u16* __restrict__ VTp, u16* __restrict__ o)
{
  __shared__ u16 Ks[128 * 64];      // (key, d)        16 KB
  __shared__ u16 Vs[64 * 128];      // (d, key)        16 KB
  __shared__ u16 Ps[4 * 16 * 64];   // per-wave (q,key) 8 KB

  const int tid  = threadIdx.x;
  const int lane = tid & 63;
  const int w    = tid >> 6;
  const int quad = lane >> 4;
  const int c16  = lane & 15;

  // XCD-locality remap: b -> (h, qb0)
  const int b    = blockIdx.x;
  const int xcd  = b & 7;
  const int idx  = b >> 3;               // 0..127, ascending in launch order
  const int h    = xcd * 2 + (idx >> 6); // heads {2x, 2x+1}
  const int qb0  = (idx & 63) * 64;      // qb ascending within XCD

  const long qrow = qb0 + w * 16 + c16;
  const bf16x8 aq0 = *(const bf16x8*)(&Qb[qrow * 1024 + h * 64 + quad * 8]);
  const bf16x8 aq1 = *(const bf16x8*)(&Qb[qrow * 1024 + h * 64 + 32 + quad * 8]);

  // K staging: wave w covers key-rows [w*32, +32): 4 gll16 x (8 rows x 8 slots)
  // stored slot = chunk ^ (key & 7)
  const int krow = lane >> 3;                  // 0..7
  const int kchk = (lane & 7) ^ krow;
  const u16* gK = &Kp[((long)h * 4608 + qb0 + w * 32 + krow) * 64 + kchk * 8];
  u16* const lK = &Ks[(w * 32) * 64];

  // V staging: wave w covers d-rows [w*16, +16): 4 gll16, each 4 rows x 16
  // slots. Stored slot must be chunk ^ (d & 15): gll16 #k holds d-rows
  // w*16 + 4k + (lane>>4), so the XOR term is (4k + lane>>4) per gll16.
  const int vrow = lane >> 4;                  // 0..3
  const u16* gV[4]; u16* lV[4];
#pragma unroll
  for (int k = 0; k < 4; ++k) {
    const int dlo  = 4 * k + vrow;             // d & 15 for this lane, gll16 #k
    const int vchk = (lane & 15) ^ dlo;        // global chunk stored at slot lane&15
    gV[k] = &VTp[((long)h * 64 + w * 16 + dlo) * 4608 + qb0 + vchk * 8];
    lV[k] = &Vs[(w * 16 + 4 * k) * 128];
  }

  const int off0 = (quad ^ (c16 & 7)) * 8;         // Ks / Ps slots
  const int off1 = ((4 + quad) ^ (c16 & 7)) * 8;
  const u16* rK[4]; const u16* rV[4];
#pragma unroll
  for (int i = 0; i < 4; ++i) {
    rK[i] = &Ks[(i * 16 + c16) * 64];
    rV[i] = &Vs[(i * 16 + c16) * 128];
  }
  int voff[2][2];
#pragma unroll
  for (int hf = 0; hf < 2; ++hf) {
    voff[hf][0] = ((hf * 8 + quad) ^ c16) * 8;       // Vs slots (16-chunk rows)
    voff[hf][1] = ((hf * 8 + 4 + quad) ^ c16) * 8;
  }
  u16* const Pw = &Ps[w * 1024];
  const u16* rP = &Pw[c16 * 64];

  const int dbase = c16 - 16 * w - quad * 4;   // delta = dbase + t*128 + hf*64 + tcol*16 - r

  f32x4 acc[4];
#pragma unroll
  for (int dt = 0; dt < 4; ++dt) acc[dt] = f32x4{0.f, 0.f, 0.f, 0.f};
  float rsum[4] = {0.f, 0.f, 0.f, 0.f};

  for (int t = 0; t < 5; ++t) {
    __syncthreads();
    gll16(gK,            lK);
    gll16(gK +  8 * 64,  lK +  8 * 64);
    gll16(gK + 16 * 64,  lK + 16 * 64);
    gll16(gK + 24 * 64,  lK + 24 * 64);
#pragma unroll
    for (int k = 0; k < 4; ++k) { gll16(gV[k], lV[k]); gV[k] += 128; }
    gK += 128 * 64;
    __syncthreads();

#pragma unroll
    for (int hf = 0; hf < 2; ++hf) {
      if (t == 4 && hf == 1) break;   // half-pass 9 fully out-of-band (uniform)

      // S = Q K^T ; mask+exp ; P -> LDS (per-wave, in-order DS pipeline)
#pragma unroll
      for (int tcol = 0; tcol < 4; ++tcol) {
        const u16* kb = rK[tcol] + hf * 64 * 64;
        const bf16x8 bk0 = *(const bf16x8*)(kb + off0);
        const bf16x8 bk1 = *(const bf16x8*)(kb + off1);
        f32x4 s = f32x4{0.f, 0.f, 0.f, 0.f};
        s = MFMA16(aq0, bk0, s);
        s = MFMA16(aq1, bk1, s);
#pragma unroll
        for (int r = 0; r < 4; ++r) {
          const int delta = dbase + t * 128 + hf * 64 + tcol * 16 - r;
          const float p = ((u32)delta < 512u) ? __expf(s[r]) : 0.f;
          rsum[r] += p;
          const int qi = quad * 4 + r;
          const int kc = tcol * 16 + c16;
          Pw[qi * 64 + (((kc >> 3) ^ (qi & 7)) * 8) + (kc & 7)] = f2b(p);
        }
      }

      // O += P V
      const bf16x8 ap0 = *(const bf16x8*)(rP + off0);
      const bf16x8 ap1 = *(const bf16x8*)(rP + off1);
#pragma unroll
      for (int dt = 0; dt < 4; ++dt) {
        const bf16x8 bv0 = *(const bf16x8*)(rV[dt] + voff[hf][0]);
        const bf16x8 bv1 = *(const bf16x8*)(rV[dt] + voff[hf][1]);
        acc[dt] = MFMA16(ap0, bv0, acc[dt]);
        acc[dt] = MFMA16(ap1, bv1, acc[dt]);
      }
    }
  }

  // row-sum reduction across the 16 lanes holding each C-row
#pragma unroll
  for (int off = 1; off < 16; off <<= 1)
#pragma unroll
    for (int r = 0; r < 4; ++r)
      rsum[r] += __shfl_xor(rsum[r], off, 64);

  const int qp = qb0 + w * 16 + quad * 4;
#pragma unroll
  for (int r = 0; r < 4; ++r) {
    const float inv = 1.f / rsum[r];
#pragma unroll
    for (int dt = 0; dt < 4; ++dt)
      o[(long)(qp + r) * 1024 + h * 64 + dt * 16 + c16] = f2b(acc[dt][r] * inv);
  }
}

// ---------------------------------------------------------------------------
extern "C" void kernel_launch(void* const* d_in, const int* in_sizes, int n_in,
                              void* d_out, int out_size, void* d_ws, size_t ws_size,
                              hipStream_t stream)
{
  const float* x    = (const float*)d_in[0];   // (4096, 1024)
  const float* Wqkv = (const float*)d_in[1];   // (3072, 1024)
  const float* bqkv = (const float*)d_in[2];   // (3072,)
  const float* Wout = (const float*)d_in[3];   // (1024, 1024)
  const float* bout = (const float*)d_in[4];   // (1024,)
  float* out = (float*)d_out;                  // (4096, 1024)

  // ws layout (u16 elements); xb|wqkvb|woutb contiguous for cvt_all
  u16* xb    = (u16*)d_ws;                         // 4096*1024
  u16* wqkvb = xb    + (size_t)4096 * 1024;        // 3072*1024
  u16* woutb = wqkvb + (size_t)3072 * 1024;        // 1024*1024
  u16* Qb    = woutb + (size_t)1024 * 1024;        // 4096*1024
  u16* Kp    = Qb    + (size_t)4096 * 1024;        // 16*4608*64
  u16* VTp   = Kp    + (size_t)16 * 4608 * 64;     // 16*64*4608
  u16* o     = VTp   + (size_t)16 * 4608 * 64;     // 4096*1024

  // 1048576 convert chunks + 131072 pad-zero chunks
  cvt_all<<<(1048576 + 131072) / 256, 256, 0, stream>>>(x, Wqkv, Wout, xb, Kp, VTp);

  gemm_qkv<<<dim3(3072 / 128, 4096 / 64), 256, 0, stream>>>(
      xb, wqkvb, bqkv, Qb, Kp, VTp);
  swa_fused<<<1024, 256, 0, stream>>>(Qb, Kp, VTp, o);
  gemm_out<<<dim3(1024 / 64, 4096 / 64), 256, 0, stream>>>(o, woutb, bout, out);
}